// Round 4
// baseline (1182.247 us; speedup 1.0000x reference)
//
#include <hip/hip_runtime.h>

// CLAGCN forward on MI355X.
// R1: stats 2-level reduction. R2: multi-block scan.
// R3: (a) aggregation source staged in bf16 (GEMM writes bf16) -> halves
//     gather bytes + working set; (b) g1/g2 agg pair fused into one dual
//     dispatch (grid.y=2) for L2 reuse; (c) combine fused into consumer
//     GEMM X-load; (d) stats via per-block partials (no atomics/memsets).

#define DFEAT 128

__device__ __forceinline__ unsigned short f2bf(float f) {
    unsigned u = __float_as_uint(f);
    u += 0x7fffu + ((u >> 16) & 1u);
    return (unsigned short)(u >> 16);
}
__device__ __forceinline__ float4 bf4tof4(ushort4 u) {
    return make_float4(__uint_as_float((unsigned)u.x << 16),
                       __uint_as_float((unsigned)u.y << 16),
                       __uint_as_float((unsigned)u.z << 16),
                       __uint_as_float((unsigned)u.w << 16));
}

// ---------------- CSR build ----------------
__global__ void count_kernel(const int* __restrict__ dst, int* __restrict__ counts, int E) {
    int i = blockIdx.x * blockDim.x + threadIdx.x;
    if (i < E) atomicAdd(&counts[dst[i]], 1);
}

__global__ __launch_bounds__(256) void blocksum_kernel(const int* __restrict__ c1,
                                                       const int* __restrict__ c2,
                                                       int* __restrict__ bs, int n, int nb) {
    const int* c = blockIdx.y ? c2 : c1;
    int* out = bs + (size_t)blockIdx.y * nb;
    int t = threadIdx.x;
    int base = blockIdx.x * 2048 + t * 8;
    int s = 0;
#pragma unroll
    for (int i = 0; i < 8; ++i) {
        int idx = base + i;
        if (idx < n) s += c[idx];
    }
    __shared__ int red[256];
    red[t] = s;
    __syncthreads();
    for (int o = 128; o > 0; o >>= 1) {
        if (t < o) red[t] += red[t + o];
        __syncthreads();
    }
    if (t == 0) out[blockIdx.x] = red[0];
}

__global__ void scansums_kernel(int* __restrict__ bs, int nb, int* __restrict__ rp1,
                                int* __restrict__ rp2, int n, int E) {
    int t = threadIdx.x;
    if (t < 2) {
        int* b = bs + (size_t)t * nb;
        int run = 0;
        for (int i = 0; i < nb; ++i) {
            int v = b[i];
            b[i] = run;
            run += v;
        }
        (t ? rp2 : rp1)[n] = E;
    }
}

__global__ __launch_bounds__(256) void writerp_kernel(const int* __restrict__ c1,
                                                      const int* __restrict__ c2,
                                                      const int* __restrict__ bs,
                                                      int* __restrict__ rp1, int* __restrict__ rp2,
                                                      float* __restrict__ dv1,
                                                      float* __restrict__ dv2, int n, int nb) {
    const int* c = blockIdx.y ? c2 : c1;
    int* rp = blockIdx.y ? rp2 : rp1;
    float* dv = blockIdx.y ? dv2 : dv1;
    int boff = bs[(size_t)blockIdx.y * nb + blockIdx.x];
    int t = threadIdx.x;
    int base = blockIdx.x * 2048 + t * 8;
    int v[8];
    int s = 0;
#pragma unroll
    for (int i = 0; i < 8; ++i) {
        int idx = base + i;
        v[i] = (idx < n) ? c[idx] : 0;
        s += v[i];
    }
    __shared__ int red[256];
    red[t] = s;
    __syncthreads();
    for (int o = 1; o < 256; o <<= 1) {
        int x = (t >= o) ? red[t - o] : 0;
        __syncthreads();
        red[t] += x;
        __syncthreads();
    }
    int run = boff + red[t] - s;
#pragma unroll
    for (int i = 0; i < 8; ++i) {
        int idx = base + i;
        if (idx < n) {
            rp[idx] = run;
            dv[idx] = rsqrtf((float)(v[i] + 1));  // +1 self-loop
            run += v[i];
        }
    }
}

__global__ void fill_kernel(const int* __restrict__ src, const int* __restrict__ dst,
                            const int* __restrict__ row_ptr, int* __restrict__ fill,
                            int* __restrict__ csr_src, float* __restrict__ csr_norm,
                            const float* __restrict__ dinv, int E) {
    int i = blockIdx.x * blockDim.x + threadIdx.x;
    if (i >= E) return;
    int d = dst[i];
    int s = src[i];
    int pos = row_ptr[d] + atomicAdd(&fill[d], 1);
    csr_src[pos] = s;
    csr_norm[pos] = dinv[s] * dinv[d];
}

// ---------------- dual aggregation (both graphs in one dispatch) ----------------
// grid.y selects graph. Source h is bf16 (halved gather bytes); acc/out fp32.
template <int FV, int GROUP>
__global__ void dualagg_kernel(const unsigned short* __restrict__ h1,
                               const unsigned short* __restrict__ h2,
                               const int* __restrict__ rp1, const int* __restrict__ cs1,
                               const float* __restrict__ cn1, const float* __restrict__ dv1,
                               const int* __restrict__ rp2, const int* __restrict__ cs2,
                               const float* __restrict__ cn2, const float* __restrict__ dv2,
                               const float* __restrict__ bias, float* __restrict__ o1,
                               float* __restrict__ o2, int n) {
    constexpr int COLS = FV * 4;
    const unsigned short* h;
    const int *rp, *cs;
    const float *cn, *dv;
    float* out;
    if (blockIdx.y == 0) { h = h1; rp = rp1; cs = cs1; cn = cn1; dv = dv1; out = o1; }
    else                 { h = h2; rp = rp2; cs = cs2; cn = cn2; dv = dv2; out = o2; }
    int gid = (blockIdx.x * blockDim.x + threadIdx.x) / GROUP;
    int lane = threadIdx.x & (GROUP - 1);
    if (gid >= n) return;
    bool act = (lane < FV);
    float dn = dv[gid];
    float4 acc = make_float4(0.f, 0.f, 0.f, 0.f);
    if (act) {
        float4 hv = bf4tof4(((const ushort4*)(h + (size_t)gid * COLS))[lane]);
        float w = dn * dn;  // self-loop norm
        acc.x = hv.x * w; acc.y = hv.y * w; acc.z = hv.z * w; acc.w = hv.w * w;
    }
    int e0 = rp[gid], e1 = rp[gid + 1];
    int e = e0;
    for (; e + 4 <= e1; e += 4) {
        int s0 = cs[e + 0], s1 = cs[e + 1], s2 = cs[e + 2], s3 = cs[e + 3];
        float w0 = cn[e + 0], w1 = cn[e + 1], w2 = cn[e + 2], w3 = cn[e + 3];
        if (act) {
            float4 h0 = bf4tof4(((const ushort4*)(h + (size_t)s0 * COLS))[lane]);
            float4 h1v = bf4tof4(((const ushort4*)(h + (size_t)s1 * COLS))[lane]);
            float4 h2v = bf4tof4(((const ushort4*)(h + (size_t)s2 * COLS))[lane]);
            float4 h3v = bf4tof4(((const ushort4*)(h + (size_t)s3 * COLS))[lane]);
            acc.x = fmaf(w0, h0.x, acc.x); acc.y = fmaf(w0, h0.y, acc.y);
            acc.z = fmaf(w0, h0.z, acc.z); acc.w = fmaf(w0, h0.w, acc.w);
            acc.x = fmaf(w1, h1v.x, acc.x); acc.y = fmaf(w1, h1v.y, acc.y);
            acc.z = fmaf(w1, h1v.z, acc.z); acc.w = fmaf(w1, h1v.w, acc.w);
            acc.x = fmaf(w2, h2v.x, acc.x); acc.y = fmaf(w2, h2v.y, acc.y);
            acc.z = fmaf(w2, h2v.z, acc.z); acc.w = fmaf(w2, h2v.w, acc.w);
            acc.x = fmaf(w3, h3v.x, acc.x); acc.y = fmaf(w3, h3v.y, acc.y);
            acc.z = fmaf(w3, h3v.z, acc.z); acc.w = fmaf(w3, h3v.w, acc.w);
        }
    }
    for (; e < e1; ++e) {
        int s = cs[e];
        float w = cn[e];
        if (act) {
            float4 hv = bf4tof4(((const ushort4*)(h + (size_t)s * COLS))[lane]);
            acc.x = fmaf(w, hv.x, acc.x);
            acc.y = fmaf(w, hv.y, acc.y);
            acc.z = fmaf(w, hv.z, acc.z);
            acc.w = fmaf(w, hv.w, acc.w);
        }
    }
    if (act) {
        float4 b = ((const float4*)bias)[lane];
        float4 r = make_float4(acc.x + b.x, acc.y + b.y, acc.z + b.z, acc.w + b.w);
        ((float4*)(out + (size_t)gid * COLS))[lane] = r;
    }
}

// ---------------- GEMM (optionally with fused combine), bf16 output ----------------
// Y[r, ocol + c] = sum_k x[r,k] * W[k,c], K fixed 128.
// FUSE: x = w1*relu(A*scA+shA) + w2*relu(B*scB+shB) computed during X-load.
template <int CG, int RPT, bool FUSE>
__global__ __launch_bounds__(256) void gemm_kernel(
    const float* __restrict__ X, const float* __restrict__ B2, const float* __restrict__ ss,
    const float* __restrict__ wout, const float* __restrict__ W,
    unsigned short* __restrict__ Y, int nrows, int fout, int ostride, int ocol) {
    __shared__ float Ws[32][CG * 4];
    __shared__ float Xs[64][32];
    int tid = threadIdx.x;
    int row0 = blockIdx.x * 64;
    int cg = tid % CG;
    int rg = tid / CG;
    float w1 = 0.f, w2 = 0.f;
    if (FUSE) { w1 = wout[0]; w2 = wout[1]; }
    float4 acc[RPT];
#pragma unroll
    for (int i = 0; i < RPT; ++i) acc[i] = make_float4(0.f, 0.f, 0.f, 0.f);
    for (int kc = 0; kc < 4; ++kc) {
        for (int i = tid; i < 32 * CG; i += 256) {
            int r = i / CG, c = i % CG;
            float4 w;
            if ((c * 4 + 3) < fout) {
                w = *(const float4*)(W + (size_t)(kc * 32 + r) * fout + c * 4);
            } else {
                float t0 = (c * 4 + 0) < fout ? W[(size_t)(kc * 32 + r) * fout + c * 4 + 0] : 0.f;
                float t1 = (c * 4 + 1) < fout ? W[(size_t)(kc * 32 + r) * fout + c * 4 + 1] : 0.f;
                float t2 = (c * 4 + 2) < fout ? W[(size_t)(kc * 32 + r) * fout + c * 4 + 2] : 0.f;
                float t3 = (c * 4 + 3) < fout ? W[(size_t)(kc * 32 + r) * fout + c * 4 + 3] : 0.f;
                w = make_float4(t0, t1, t2, t3);
            }
            *(float4*)&Ws[r][c * 4] = w;
        }
        for (int i = tid; i < 64 * 8; i += 256) {
            int r = i / 8, c = i % 8;
            int gr = row0 + r;
            int col0 = kc * 32 + c * 4;
            float4 v = make_float4(0.f, 0.f, 0.f, 0.f);
            if (gr < nrows) {
                float4 a = *(const float4*)(X + (size_t)gr * DFEAT + col0);
                if (FUSE) {
                    float4 b = *(const float4*)(B2 + (size_t)gr * DFEAT + col0);
                    float4 scA = *(const float4*)(ss + col0);
                    float4 shA = *(const float4*)(ss + DFEAT + col0);
                    float4 scB = *(const float4*)(ss + 2 * DFEAT + col0);
                    float4 shB = *(const float4*)(ss + 3 * DFEAT + col0);
                    v.x = w1 * fmaxf(fmaf(a.x, scA.x, shA.x), 0.f) +
                          w2 * fmaxf(fmaf(b.x, scB.x, shB.x), 0.f);
                    v.y = w1 * fmaxf(fmaf(a.y, scA.y, shA.y), 0.f) +
                          w2 * fmaxf(fmaf(b.y, scB.y, shB.y), 0.f);
                    v.z = w1 * fmaxf(fmaf(a.z, scA.z, shA.z), 0.f) +
                          w2 * fmaxf(fmaf(b.z, scB.z, shB.z), 0.f);
                    v.w = w1 * fmaxf(fmaf(a.w, scA.w, shA.w), 0.f) +
                          w2 * fmaxf(fmaf(b.w, scB.w, shB.w), 0.f);
                } else {
                    v = a;
                }
            }
            *(float4*)&Xs[r][c * 4] = v;
        }
        __syncthreads();
#pragma unroll
        for (int k = 0; k < 32; ++k) {
            float4 w = *(float4*)&Ws[k][cg * 4];
#pragma unroll
            for (int i = 0; i < RPT; ++i) {
                float a = Xs[rg * RPT + i][k];
                acc[i].x = fmaf(a, w.x, acc[i].x);
                acc[i].y = fmaf(a, w.y, acc[i].y);
                acc[i].z = fmaf(a, w.z, acc[i].z);
                acc[i].w = fmaf(a, w.w, acc[i].w);
            }
        }
        __syncthreads();
    }
    if (cg * 4 < fout) {
#pragma unroll
        for (int i = 0; i < RPT; ++i) {
            int r = row0 + rg * RPT + i;
            if (r < nrows) {
                ushort4 o;
                o.x = f2bf(acc[i].x);
                o.y = f2bf(acc[i].y);
                o.z = f2bf(acc[i].z);
                o.w = f2bf(acc[i].w);
                *(ushort4*)(Y + (size_t)r * ostride + ocol + cg * 4) = o;
            }
        }
    }
}

// ---------------- BN statistics: per-block partials (no atomics) ----------------
// grid: (nbst, 2). partials[(y*nbst + x)*256 + col] = sum, +128 = sumsq.
__global__ __launch_bounds__(256) void stats2_kernel(const float* __restrict__ A,
                                                     const float* __restrict__ B,
                                                     float* __restrict__ part, int nrows) {
    __shared__ float red1[256];
    __shared__ float red2[256];
    int t = threadIdx.x;
    int col = t & 127;
    int rg = t >> 7;
    const float* src = (blockIdx.y == 0) ? A : B;
    int r0 = blockIdx.x * 128 + rg * 64;
    int r1 = min(r0 + 64, nrows);
    float s = 0.f, s2 = 0.f;
    for (int r = r0; r < r1; ++r) {
        float v = src[(size_t)r * DFEAT + col];
        s += v;
        s2 = fmaf(v, v, s2);
    }
    red1[t] = s;
    red2[t] = s2;
    __syncthreads();
    if (t < 128) {
        float* p = part + ((size_t)blockIdx.y * gridDim.x + blockIdx.x) * 256;
        p[col] = red1[t] + red1[t + 128];
        p[128 + col] = red2[t] + red2[t + 128];
    }
}

// ---------------- BN scale/shift + sigmoid gates from row N-1 ----------------
__global__ __launch_bounds__(128) void gate_prep_kernel(
    const float* __restrict__ part, int nbst,
    const float* __restrict__ preA, const float* __restrict__ preB,
    const float* __restrict__ gamma, const float* __restrict__ beta,
    const float* __restrict__ gwA, const float* __restrict__ gbA,
    const float* __restrict__ gwB, const float* __restrict__ gbB,
    float* __restrict__ ss, float* __restrict__ wout, int nrows) {
    __shared__ float red[128];
    __shared__ float dotA_s;
    int t = threadIdx.x;
    float sA = 0.f, qA = 0.f, sB = 0.f, qB = 0.f;
    for (int b = 0; b < nbst; ++b) {
        const float* pa = part + (size_t)b * 256;
        const float* pb = part + (size_t)(nbst + b) * 256;
        sA += pa[t]; qA += pa[128 + t];
        sB += pb[t]; qB += pb[128 + t];
    }
    float invN = 1.f / (float)nrows;
    float meanA = sA * invN;
    float varA = qA * invN - meanA * meanA;
    float scA = gamma[t] * rsqrtf(varA + 1e-5f);
    float shA = beta[t] - meanA * scA;
    ss[t] = scA;
    ss[DFEAT + t] = shA;
    float meanB = sB * invN;
    float varB = qB * invN - meanB * meanB;
    float scB = gamma[t] * rsqrtf(varB + 1e-5f);
    float shB = beta[t] - meanB * scB;
    ss[2 * DFEAT + t] = scB;
    ss[3 * DFEAT + t] = shB;
    float av = fmaxf(fmaf(preA[(size_t)(nrows - 1) * DFEAT + t], scA, shA), 0.f);
    red[t] = av * gwA[t];
    __syncthreads();
    for (int s = 64; s > 0; s >>= 1) {
        if (t < s) red[t] += red[t + s];
        __syncthreads();
    }
    if (t == 0) dotA_s = red[0];
    __syncthreads();
    float bv = fmaxf(fmaf(preB[(size_t)(nrows - 1) * DFEAT + t], scB, shB), 0.f);
    red[t] = bv * gwB[t];
    __syncthreads();
    for (int s = 64; s > 0; s >>= 1) {
        if (t < s) red[t] += red[t + s];
        __syncthreads();
    }
    if (t == 0) {
        float s1 = 1.f / (1.f + expf(-(dotA_s + gbA[0])));
        float s2 = 1.f / (1.f + expf(-(red[0] + gbB[0])));
        float tt = s1 + s2;
        wout[0] = s1 / tt;
        wout[1] = s2 / tt;
    }
}

// gates for the final layer (no BN), F = nclass
__global__ __launch_bounds__(64) void gate_final_kernel(
    const float* __restrict__ p1, const float* __restrict__ p2,
    const float* __restrict__ w1v, const float* __restrict__ b1,
    const float* __restrict__ w2v, const float* __restrict__ b2,
    float* __restrict__ wout, int nrows, int nclass) {
    __shared__ float red[64];
    __shared__ float dot1_s;
    int t = threadIdx.x;
    float v = (t < nclass) ? p1[(size_t)(nrows - 1) * nclass + t] * w1v[t] : 0.f;
    red[t] = v;
    __syncthreads();
    for (int s = 32; s > 0; s >>= 1) {
        if (t < s) red[t] += red[t + s];
        __syncthreads();
    }
    if (t == 0) dot1_s = red[0];
    __syncthreads();
    v = (t < nclass) ? p2[(size_t)(nrows - 1) * nclass + t] * w2v[t] : 0.f;
    red[t] = v;
    __syncthreads();
    for (int s = 32; s > 0; s >>= 1) {
        if (t < s) red[t] += red[t + s];
        __syncthreads();
    }
    if (t == 0) {
        float s1 = 1.f / (1.f + expf(-(dot1_s + b1[0])));
        float s2 = 1.f / (1.f + expf(-(red[0] + b2[0])));
        float tt = s1 + s2;
        wout[0] = s1 / tt;
        wout[1] = s2 / tt;
    }
}

__global__ __launch_bounds__(256) void mix_kernel(const float* __restrict__ p1,
                                                  const float* __restrict__ p2,
                                                  const float* __restrict__ wout,
                                                  float* __restrict__ o, int n4) {
    int idx = blockIdx.x * blockDim.x + threadIdx.x;
    if (idx >= n4) return;
    float w1 = wout[0], w2 = wout[1];
    float4 a = *(const float4*)(p1 + (size_t)idx * 4);
    float4 b = *(const float4*)(p2 + (size_t)idx * 4);
    float4 r = make_float4(w1 * a.x + w2 * b.x, w1 * a.y + w2 * b.y, w1 * a.z + w2 * b.z,
                           w1 * a.w + w2 * b.w);
    *(float4*)(o + (size_t)idx * 4) = r;
}

extern "C" void kernel_launch(void* const* d_in, const int* in_sizes, int n_in, void* d_out,
                              int out_size, void* d_ws, size_t ws_size, hipStream_t stream) {
    (void)n_in; (void)out_size; (void)ws_size;
    const int N = in_sizes[0] / DFEAT;        // 50000
    const int E = in_sizes[4] / 2;            // 800000
    const int NC = in_sizes[15];              // 40

    const float* x1a = (const float*)d_in[0];
    const float* x1b = (const float*)d_in[1];
    const float* x2a = (const float*)d_in[2];
    const float* x2b = (const float*)d_in[3];
    const int* ei1 = (const int*)d_in[4];
    const int* ei2 = (const int*)d_in[5];
    const float* Wi = (const float*)d_in[6];
    const float* bi = (const float*)d_in[7];
    const float* gi = (const float*)d_in[8];
    const float* bei = (const float*)d_in[9];
    const float* Wm = (const float*)d_in[10];
    const float* bm = (const float*)d_in[11];
    const float* gm = (const float*)d_in[12];
    const float* bem = (const float*)d_in[13];
    const float* Wf = (const float*)d_in[14];
    const float* bf = (const float*)d_in[15];
    const float* fc1w1_W = (const float*)d_in[16];
    const float* fc1w1_b = (const float*)d_in[17];
    const float* fc1w2_W = (const float*)d_in[18];
    const float* fc1w2_b = (const float*)d_in[19];
    const float* aws_w1_W = (const float*)d_in[20];
    const float* aws_w1_b = (const float*)d_in[21];
    const float* aws_w2_W = (const float*)d_in[22];
    const float* aws_w2_b = (const float*)d_in[23];
    const float* fcw1_W = (const float*)d_in[24];
    const float* fcw1_b = (const float*)d_in[25];
    const float* fcw2_W = (const float*)d_in[26];
    const float* fcw2_b = (const float*)d_in[27];

    char* ws = (char*)d_ws;
    size_t off = 0;
    auto alloc = [&](size_t bytes) -> char* {
        char* p = ws + off;
        off += (bytes + 255) & ~(size_t)255;
        return p;
    };
    float* A = (float*)alloc((size_t)N * DFEAT * 4);   // pre-BN branch 1
    float* B = (float*)alloc((size_t)N * DFEAT * 4);   // pre-BN branch 2
    unsigned short* H1 = (unsigned short*)alloc((size_t)N * DFEAT * 2);  // bf16 staging
    unsigned short* H2 = (unsigned short*)alloc((size_t)N * DFEAT * 2);  // bf16 staging / P40
    int* rp1 = (int*)alloc((size_t)(N + 1) * 4);
    int* rp2 = (int*)alloc((size_t)(N + 1) * 4);
    int* cntb = (int*)alloc((size_t)2 * N * 4);  // cnt1|cnt2 contiguous (1 memset)
    int* cnt1 = cntb;
    int* cnt2 = cntb + N;
    int* flb = (int*)alloc((size_t)2 * N * 4);   // fl1|fl2 contiguous (1 memset)
    int* fl1 = flb;
    int* fl2 = flb + N;
    float* dv1 = (float*)alloc((size_t)N * 4);
    float* dv2 = (float*)alloc((size_t)N * 4);
    int* cs1 = (int*)alloc((size_t)E * 4);
    float* cn1 = (float*)alloc((size_t)E * 4);
    int* cs2 = (int*)alloc((size_t)E * 4);
    float* cn2 = (float*)alloc((size_t)E * 4);
    int nbst = (N + 127) / 128;  // 391
    float* part = (float*)alloc((size_t)2 * nbst * 256 * 4);
    float* ssbuf = (float*)alloc(2048);
    float* wout = (float*)alloc(256);
    int nb = (N + 2047) / 2048;  // 25
    int* bsums = (int*)alloc((size_t)2 * nb * 4);

    const int* src1 = ei1;
    const int* dst1 = ei1 + E;
    const int* src2 = ei2;
    const int* dst2 = ei2 + E;

    int ebl = (E + 255) / 256;
    int gemmbl = (N + 63) / 64;
    dim3 agggrid((N * 32 + 255) / 256, 2);
    dim3 agggrid40((N * 16 + 255) / 256, 2);
    dim3 statgrid(nbst, 2);
    dim3 scangrid(nb, 2);

    // ---- CSR build ----
    hipMemsetAsync(cntb, 0, (size_t)2 * N * 4, stream);
    hipMemsetAsync(flb, 0, (size_t)2 * N * 4, stream);
    count_kernel<<<ebl, 256, 0, stream>>>(dst1, cnt1, E);
    count_kernel<<<ebl, 256, 0, stream>>>(dst2, cnt2, E);
    blocksum_kernel<<<scangrid, 256, 0, stream>>>(cnt1, cnt2, bsums, N, nb);
    scansums_kernel<<<1, 64, 0, stream>>>(bsums, nb, rp1, rp2, N, E);
    writerp_kernel<<<scangrid, 256, 0, stream>>>(cnt1, cnt2, bsums, rp1, rp2, dv1, dv2, N, nb);
    fill_kernel<<<ebl, 256, 0, stream>>>(src1, dst1, rp1, fl1, cs1, cn1, dv1, E);
    fill_kernel<<<ebl, 256, 0, stream>>>(src2, dst2, rp2, fl2, cs2, cn2, dv2, E);

    // ---- Layer 1 ----
    gemm_kernel<16, 4, false><<<gemmbl, 256, 0, stream>>>(x1a, nullptr, nullptr, nullptr, Wi, H1,
                                                          N, 64, DFEAT, 0);
    gemm_kernel<16, 4, false><<<gemmbl, 256, 0, stream>>>(x1b, nullptr, nullptr, nullptr,
                                                          Wi + 128 * 64, H1, N, 64, DFEAT, 64);
    gemm_kernel<16, 4, false><<<gemmbl, 256, 0, stream>>>(x2a, nullptr, nullptr, nullptr, Wi, H2,
                                                          N, 64, DFEAT, 0);
    gemm_kernel<16, 4, false><<<gemmbl, 256, 0, stream>>>(x2b, nullptr, nullptr, nullptr,
                                                          Wi + 128 * 64, H2, N, 64, DFEAT, 64);
    dualagg_kernel<32, 32><<<agggrid, 256, 0, stream>>>(H1, H2, rp1, cs1, cn1, dv1, rp2, cs2, cn2,
                                                        dv2, bi, A, B, N);
    stats2_kernel<<<statgrid, 256, 0, stream>>>(A, B, part, N);
    gate_prep_kernel<<<1, 128, 0, stream>>>(part, nbst, A, B, gi, bei, fc1w1_W, fc1w1_b, fc1w2_W,
                                            fc1w2_b, ssbuf, wout, N);

    // ---- Middle layer 0 (combine fused into GEMM X-load) ----
    gemm_kernel<32, 8, true><<<gemmbl, 256, 0, stream>>>(A, B, ssbuf, wout, Wm, H1, N, 128, 128, 0);
    dualagg_kernel<32, 32><<<agggrid, 256, 0, stream>>>(H1, H1, rp1, cs1, cn1, dv1, rp2, cs2, cn2,
                                                        dv2, bm, A, B, N);
    stats2_kernel<<<statgrid, 256, 0, stream>>>(A, B, part, N);
    gate_prep_kernel<<<1, 128, 0, stream>>>(part, nbst, A, B, gm, bem, aws_w1_W, aws_w1_b,
                                            aws_w2_W, aws_w2_b, ssbuf, wout, N);

    // ---- Middle layer 1 ----
    gemm_kernel<32, 8, true><<<gemmbl, 256, 0, stream>>>(A, B, ssbuf, wout, Wm + 128 * 128, H1, N,
                                                         128, 128, 0);
    dualagg_kernel<32, 32><<<agggrid, 256, 0, stream>>>(H1, H1, rp1, cs1, cn1, dv1, rp2, cs2, cn2,
                                                        dv2, bm + 128, A, B, N);
    stats2_kernel<<<statgrid, 256, 0, stream>>>(A, B, part, N);
    gate_prep_kernel<<<1, 128, 0, stream>>>(part, nbst, A, B, gm + 128, bem + 128, aws_w1_W + 128,
                                            aws_w1_b + 1, aws_w2_W + 128, aws_w2_b + 1, ssbuf,
                                            wout, N);

    // ---- Final layer ----
    float* out0 = (float*)d_out;
    float* p1 = out0 + (size_t)N * NC;
    float* p2 = out0 + (size_t)2 * N * NC;
    gemm_kernel<16, 4, true><<<gemmbl, 256, 0, stream>>>(A, B, ssbuf, wout, Wf, H2, N, NC, NC, 0);
    dualagg_kernel<10, 16><<<agggrid40, 256, 0, stream>>>(H2, H2, rp1, cs1, cn1, dv1, rp2, cs2,
                                                          cn2, dv2, bf, p1, p2, N);
    gate_final_kernel<<<1, 64, 0, stream>>>(p1, p2, fcw1_W, fcw1_b, fcw2_W, fcw2_b, wout, N, NC);
    mix_kernel<<<(N * NC / 4 + 255) / 256, 256, 0, stream>>>(p1, p2, wout, out0, N * NC / 4);
}

// Round 5
// 851.534 us; speedup vs baseline: 1.3884x; 1.3884x over previous
//
#include <hip/hip_runtime.h>

// CLAGCN forward on MI355X.
// R1: stats 2-level reduction. R2: multi-block scan.
// R3: bf16 agg staging, dual-graph agg dispatch, combine fused into GEMM.
// R4: REVERT stats to atomicAdd 2-level reduction — R3's "partials + 1-block
//     reduce in gate_prep" made gate_prep a 122us serial bottleneck (0.02%
//     occupancy reading 800KB). gate_prep now reads 512 floats again.

#define DFEAT 128

__device__ __forceinline__ unsigned short f2bf(float f) {
    unsigned u = __float_as_uint(f);
    u += 0x7fffu + ((u >> 16) & 1u);
    return (unsigned short)(u >> 16);
}
__device__ __forceinline__ float4 bf4tof4(ushort4 u) {
    return make_float4(__uint_as_float((unsigned)u.x << 16),
                       __uint_as_float((unsigned)u.y << 16),
                       __uint_as_float((unsigned)u.z << 16),
                       __uint_as_float((unsigned)u.w << 16));
}

// ---------------- CSR build ----------------
__global__ void count_kernel(const int* __restrict__ dst, int* __restrict__ counts, int E) {
    int i = blockIdx.x * blockDim.x + threadIdx.x;
    if (i < E) atomicAdd(&counts[dst[i]], 1);
}

__global__ __launch_bounds__(256) void blocksum_kernel(const int* __restrict__ c1,
                                                       const int* __restrict__ c2,
                                                       int* __restrict__ bs, int n, int nb) {
    const int* c = blockIdx.y ? c2 : c1;
    int* out = bs + (size_t)blockIdx.y * nb;
    int t = threadIdx.x;
    int base = blockIdx.x * 2048 + t * 8;
    int s = 0;
#pragma unroll
    for (int i = 0; i < 8; ++i) {
        int idx = base + i;
        if (idx < n) s += c[idx];
    }
    __shared__ int red[256];
    red[t] = s;
    __syncthreads();
    for (int o = 128; o > 0; o >>= 1) {
        if (t < o) red[t] += red[t + o];
        __syncthreads();
    }
    if (t == 0) out[blockIdx.x] = red[0];
}

__global__ void scansums_kernel(int* __restrict__ bs, int nb, int* __restrict__ rp1,
                                int* __restrict__ rp2, int n, int E) {
    int t = threadIdx.x;
    if (t < 2) {
        int* b = bs + (size_t)t * nb;
        int run = 0;
        for (int i = 0; i < nb; ++i) {
            int v = b[i];
            b[i] = run;
            run += v;
        }
        (t ? rp2 : rp1)[n] = E;
    }
}

__global__ __launch_bounds__(256) void writerp_kernel(const int* __restrict__ c1,
                                                      const int* __restrict__ c2,
                                                      const int* __restrict__ bs,
                                                      int* __restrict__ rp1, int* __restrict__ rp2,
                                                      float* __restrict__ dv1,
                                                      float* __restrict__ dv2, int n, int nb) {
    const int* c = blockIdx.y ? c2 : c1;
    int* rp = blockIdx.y ? rp2 : rp1;
    float* dv = blockIdx.y ? dv2 : dv1;
    int boff = bs[(size_t)blockIdx.y * nb + blockIdx.x];
    int t = threadIdx.x;
    int base = blockIdx.x * 2048 + t * 8;
    int v[8];
    int s = 0;
#pragma unroll
    for (int i = 0; i < 8; ++i) {
        int idx = base + i;
        v[i] = (idx < n) ? c[idx] : 0;
        s += v[i];
    }
    __shared__ int red[256];
    red[t] = s;
    __syncthreads();
    for (int o = 1; o < 256; o <<= 1) {
        int x = (t >= o) ? red[t - o] : 0;
        __syncthreads();
        red[t] += x;
        __syncthreads();
    }
    int run = boff + red[t] - s;
#pragma unroll
    for (int i = 0; i < 8; ++i) {
        int idx = base + i;
        if (idx < n) {
            rp[idx] = run;
            dv[idx] = rsqrtf((float)(v[i] + 1));  // +1 self-loop
            run += v[i];
        }
    }
}

__global__ void fill_kernel(const int* __restrict__ src, const int* __restrict__ dst,
                            const int* __restrict__ row_ptr, int* __restrict__ fill,
                            int* __restrict__ csr_src, float* __restrict__ csr_norm,
                            const float* __restrict__ dinv, int E) {
    int i = blockIdx.x * blockDim.x + threadIdx.x;
    if (i >= E) return;
    int d = dst[i];
    int s = src[i];
    int pos = row_ptr[d] + atomicAdd(&fill[d], 1);
    csr_src[pos] = s;
    csr_norm[pos] = dinv[s] * dinv[d];
}

// ---------------- dual aggregation (both graphs in one dispatch) ----------------
template <int FV, int GROUP>
__global__ void dualagg_kernel(const unsigned short* __restrict__ h1,
                               const unsigned short* __restrict__ h2,
                               const int* __restrict__ rp1, const int* __restrict__ cs1,
                               const float* __restrict__ cn1, const float* __restrict__ dv1,
                               const int* __restrict__ rp2, const int* __restrict__ cs2,
                               const float* __restrict__ cn2, const float* __restrict__ dv2,
                               const float* __restrict__ bias, float* __restrict__ o1,
                               float* __restrict__ o2, int n) {
    constexpr int COLS = FV * 4;
    const unsigned short* h;
    const int *rp, *cs;
    const float *cn, *dv;
    float* out;
    if (blockIdx.y == 0) { h = h1; rp = rp1; cs = cs1; cn = cn1; dv = dv1; out = o1; }
    else                 { h = h2; rp = rp2; cs = cs2; cn = cn2; dv = dv2; out = o2; }
    int gid = (blockIdx.x * blockDim.x + threadIdx.x) / GROUP;
    int lane = threadIdx.x & (GROUP - 1);
    if (gid >= n) return;
    bool act = (lane < FV);
    float dn = dv[gid];
    float4 acc = make_float4(0.f, 0.f, 0.f, 0.f);
    if (act) {
        float4 hv = bf4tof4(((const ushort4*)(h + (size_t)gid * COLS))[lane]);
        float w = dn * dn;  // self-loop norm
        acc.x = hv.x * w; acc.y = hv.y * w; acc.z = hv.z * w; acc.w = hv.w * w;
    }
    int e0 = rp[gid], e1 = rp[gid + 1];
    int e = e0;
    for (; e + 4 <= e1; e += 4) {
        int s0 = cs[e + 0], s1 = cs[e + 1], s2 = cs[e + 2], s3 = cs[e + 3];
        float w0 = cn[e + 0], w1 = cn[e + 1], w2 = cn[e + 2], w3 = cn[e + 3];
        if (act) {
            float4 h0 = bf4tof4(((const ushort4*)(h + (size_t)s0 * COLS))[lane]);
            float4 h1v = bf4tof4(((const ushort4*)(h + (size_t)s1 * COLS))[lane]);
            float4 h2v = bf4tof4(((const ushort4*)(h + (size_t)s2 * COLS))[lane]);
            float4 h3v = bf4tof4(((const ushort4*)(h + (size_t)s3 * COLS))[lane]);
            acc.x = fmaf(w0, h0.x, acc.x); acc.y = fmaf(w0, h0.y, acc.y);
            acc.z = fmaf(w0, h0.z, acc.z); acc.w = fmaf(w0, h0.w, acc.w);
            acc.x = fmaf(w1, h1v.x, acc.x); acc.y = fmaf(w1, h1v.y, acc.y);
            acc.z = fmaf(w1, h1v.z, acc.z); acc.w = fmaf(w1, h1v.w, acc.w);
            acc.x = fmaf(w2, h2v.x, acc.x); acc.y = fmaf(w2, h2v.y, acc.y);
            acc.z = fmaf(w2, h2v.z, acc.z); acc.w = fmaf(w2, h2v.w, acc.w);
            acc.x = fmaf(w3, h3v.x, acc.x); acc.y = fmaf(w3, h3v.y, acc.y);
            acc.z = fmaf(w3, h3v.z, acc.z); acc.w = fmaf(w3, h3v.w, acc.w);
        }
    }
    for (; e < e1; ++e) {
        int s = cs[e];
        float w = cn[e];
        if (act) {
            float4 hv = bf4tof4(((const ushort4*)(h + (size_t)s * COLS))[lane]);
            acc.x = fmaf(w, hv.x, acc.x);
            acc.y = fmaf(w, hv.y, acc.y);
            acc.z = fmaf(w, hv.z, acc.z);
            acc.w = fmaf(w, hv.w, acc.w);
        }
    }
    if (act) {
        float4 b = ((const float4*)bias)[lane];
        float4 r = make_float4(acc.x + b.x, acc.y + b.y, acc.z + b.z, acc.w + b.w);
        ((float4*)(out + (size_t)gid * COLS))[lane] = r;
    }
}

// ---------------- GEMM (optionally with fused combine), bf16 output ----------------
template <int CG, int RPT, bool FUSE>
__global__ __launch_bounds__(256) void gemm_kernel(
    const float* __restrict__ X, const float* __restrict__ B2, const float* __restrict__ ss,
    const float* __restrict__ wout, const float* __restrict__ W,
    unsigned short* __restrict__ Y, int nrows, int fout, int ostride, int ocol) {
    __shared__ float Ws[32][CG * 4];
    __shared__ float Xs[64][32];
    int tid = threadIdx.x;
    int row0 = blockIdx.x * 64;
    int cg = tid % CG;
    int rg = tid / CG;
    float w1 = 0.f, w2 = 0.f;
    if (FUSE) { w1 = wout[0]; w2 = wout[1]; }
    float4 acc[RPT];
#pragma unroll
    for (int i = 0; i < RPT; ++i) acc[i] = make_float4(0.f, 0.f, 0.f, 0.f);
    for (int kc = 0; kc < 4; ++kc) {
        for (int i = tid; i < 32 * CG; i += 256) {
            int r = i / CG, c = i % CG;
            float4 w;
            if ((c * 4 + 3) < fout) {
                w = *(const float4*)(W + (size_t)(kc * 32 + r) * fout + c * 4);
            } else {
                float t0 = (c * 4 + 0) < fout ? W[(size_t)(kc * 32 + r) * fout + c * 4 + 0] : 0.f;
                float t1 = (c * 4 + 1) < fout ? W[(size_t)(kc * 32 + r) * fout + c * 4 + 1] : 0.f;
                float t2 = (c * 4 + 2) < fout ? W[(size_t)(kc * 32 + r) * fout + c * 4 + 2] : 0.f;
                float t3 = (c * 4 + 3) < fout ? W[(size_t)(kc * 32 + r) * fout + c * 4 + 3] : 0.f;
                w = make_float4(t0, t1, t2, t3);
            }
            *(float4*)&Ws[r][c * 4] = w;
        }
        for (int i = tid; i < 64 * 8; i += 256) {
            int r = i / 8, c = i % 8;
            int gr = row0 + r;
            int col0 = kc * 32 + c * 4;
            float4 v = make_float4(0.f, 0.f, 0.f, 0.f);
            if (gr < nrows) {
                float4 a = *(const float4*)(X + (size_t)gr * DFEAT + col0);
                if (FUSE) {
                    float4 b = *(const float4*)(B2 + (size_t)gr * DFEAT + col0);
                    float4 scA = *(const float4*)(ss + col0);
                    float4 shA = *(const float4*)(ss + DFEAT + col0);
                    float4 scB = *(const float4*)(ss + 2 * DFEAT + col0);
                    float4 shB = *(const float4*)(ss + 3 * DFEAT + col0);
                    v.x = w1 * fmaxf(fmaf(a.x, scA.x, shA.x), 0.f) +
                          w2 * fmaxf(fmaf(b.x, scB.x, shB.x), 0.f);
                    v.y = w1 * fmaxf(fmaf(a.y, scA.y, shA.y), 0.f) +
                          w2 * fmaxf(fmaf(b.y, scB.y, shB.y), 0.f);
                    v.z = w1 * fmaxf(fmaf(a.z, scA.z, shA.z), 0.f) +
                          w2 * fmaxf(fmaf(b.z, scB.z, shB.z), 0.f);
                    v.w = w1 * fmaxf(fmaf(a.w, scA.w, shA.w), 0.f) +
                          w2 * fmaxf(fmaf(b.w, scB.w, shB.w), 0.f);
                } else {
                    v = a;
                }
            }
            *(float4*)&Xs[r][c * 4] = v;
        }
        __syncthreads();
#pragma unroll
        for (int k = 0; k < 32; ++k) {
            float4 w = *(float4*)&Ws[k][cg * 4];
#pragma unroll
            for (int i = 0; i < RPT; ++i) {
                float a = Xs[rg * RPT + i][k];
                acc[i].x = fmaf(a, w.x, acc[i].x);
                acc[i].y = fmaf(a, w.y, acc[i].y);
                acc[i].z = fmaf(a, w.z, acc[i].z);
                acc[i].w = fmaf(a, w.w, acc[i].w);
            }
        }
        __syncthreads();
    }
    if (cg * 4 < fout) {
#pragma unroll
        for (int i = 0; i < RPT; ++i) {
            int r = row0 + rg * RPT + i;
            if (r < nrows) {
                ushort4 o;
                o.x = f2bf(acc[i].x);
                o.y = f2bf(acc[i].y);
                o.z = f2bf(acc[i].z);
                o.w = f2bf(acc[i].w);
                *(ushort4*)(Y + (size_t)r * ostride + ocol + cg * 4) = o;
            }
        }
    }
}

// ---------------- BN statistics: 2-level, atomicAdd into 512 floats ----------------
// grid: (ceil(N/128), 2). blockIdx.y selects buffer A/B.
__global__ __launch_bounds__(256) void stats2_kernel(const float* __restrict__ A,
                                                     const float* __restrict__ B,
                                                     float* __restrict__ stats, int nrows) {
    __shared__ float red1[256];
    __shared__ float red2[256];
    int t = threadIdx.x;
    int col = t & 127;
    int rg = t >> 7;
    const float* src = (blockIdx.y == 0) ? A : B;
    float* st = stats + (size_t)blockIdx.y * 256;
    int r0 = blockIdx.x * 128 + rg * 64;
    int r1 = min(r0 + 64, nrows);
    float s = 0.f, s2 = 0.f;
    for (int r = r0; r < r1; ++r) {
        float v = src[(size_t)r * DFEAT + col];
        s += v;
        s2 = fmaf(v, v, s2);
    }
    red1[t] = s;
    red2[t] = s2;
    __syncthreads();
    if (t < 128) {
        float fs = red1[t] + red1[t + 128];
        float fs2 = red2[t] + red2[t + 128];
        atomicAdd(&st[col], fs);
        atomicAdd(&st[DFEAT + col], fs2);
    }
}

// ---------------- BN scale/shift + sigmoid gates from row N-1 ----------------
__global__ __launch_bounds__(128) void gate_prep_kernel(
    const float* __restrict__ statsA, const float* __restrict__ statsB,
    const float* __restrict__ preA, const float* __restrict__ preB,
    const float* __restrict__ gamma, const float* __restrict__ beta,
    const float* __restrict__ gwA, const float* __restrict__ gbA,
    const float* __restrict__ gwB, const float* __restrict__ gbB,
    float* __restrict__ ss, float* __restrict__ wout, int nrows) {
    __shared__ float red[128];
    __shared__ float dotA_s;
    int t = threadIdx.x;
    float invN = 1.f / (float)nrows;
    float meanA = statsA[t] * invN;
    float varA = statsA[DFEAT + t] * invN - meanA * meanA;
    float scA = gamma[t] * rsqrtf(varA + 1e-5f);
    float shA = beta[t] - meanA * scA;
    ss[t] = scA;
    ss[DFEAT + t] = shA;
    float meanB = statsB[t] * invN;
    float varB = statsB[DFEAT + t] * invN - meanB * meanB;
    float scB = gamma[t] * rsqrtf(varB + 1e-5f);
    float shB = beta[t] - meanB * scB;
    ss[2 * DFEAT + t] = scB;
    ss[3 * DFEAT + t] = shB;
    float av = fmaxf(fmaf(preA[(size_t)(nrows - 1) * DFEAT + t], scA, shA), 0.f);
    red[t] = av * gwA[t];
    __syncthreads();
    for (int s = 64; s > 0; s >>= 1) {
        if (t < s) red[t] += red[t + s];
        __syncthreads();
    }
    if (t == 0) dotA_s = red[0];
    __syncthreads();
    float bv = fmaxf(fmaf(preB[(size_t)(nrows - 1) * DFEAT + t], scB, shB), 0.f);
    red[t] = bv * gwB[t];
    __syncthreads();
    for (int s = 64; s > 0; s >>= 1) {
        if (t < s) red[t] += red[t + s];
        __syncthreads();
    }
    if (t == 0) {
        float s1 = 1.f / (1.f + expf(-(dotA_s + gbA[0])));
        float s2 = 1.f / (1.f + expf(-(red[0] + gbB[0])));
        float tt = s1 + s2;
        wout[0] = s1 / tt;
        wout[1] = s2 / tt;
    }
}

// gates for the final layer (no BN), F = nclass
__global__ __launch_bounds__(64) void gate_final_kernel(
    const float* __restrict__ p1, const float* __restrict__ p2,
    const float* __restrict__ w1v, const float* __restrict__ b1,
    const float* __restrict__ w2v, const float* __restrict__ b2,
    float* __restrict__ wout, int nrows, int nclass) {
    __shared__ float red[64];
    __shared__ float dot1_s;
    int t = threadIdx.x;
    float v = (t < nclass) ? p1[(size_t)(nrows - 1) * nclass + t] * w1v[t] : 0.f;
    red[t] = v;
    __syncthreads();
    for (int s = 32; s > 0; s >>= 1) {
        if (t < s) red[t] += red[t + s];
        __syncthreads();
    }
    if (t == 0) dot1_s = red[0];
    __syncthreads();
    v = (t < nclass) ? p2[(size_t)(nrows - 1) * nclass + t] * w2v[t] : 0.f;
    red[t] = v;
    __syncthreads();
    for (int s = 32; s > 0; s >>= 1) {
        if (t < s) red[t] += red[t + s];
        __syncthreads();
    }
    if (t == 0) {
        float s1 = 1.f / (1.f + expf(-(dot1_s + b1[0])));
        float s2 = 1.f / (1.f + expf(-(red[0] + b2[0])));
        float tt = s1 + s2;
        wout[0] = s1 / tt;
        wout[1] = s2 / tt;
    }
}

__global__ __launch_bounds__(256) void mix_kernel(const float* __restrict__ p1,
                                                  const float* __restrict__ p2,
                                                  const float* __restrict__ wout,
                                                  float* __restrict__ o, int n4) {
    int idx = blockIdx.x * blockDim.x + threadIdx.x;
    if (idx >= n4) return;
    float w1 = wout[0], w2 = wout[1];
    float4 a = *(const float4*)(p1 + (size_t)idx * 4);
    float4 b = *(const float4*)(p2 + (size_t)idx * 4);
    float4 r = make_float4(w1 * a.x + w2 * b.x, w1 * a.y + w2 * b.y, w1 * a.z + w2 * b.z,
                           w1 * a.w + w2 * b.w);
    *(float4*)(o + (size_t)idx * 4) = r;
}

extern "C" void kernel_launch(void* const* d_in, const int* in_sizes, int n_in, void* d_out,
                              int out_size, void* d_ws, size_t ws_size, hipStream_t stream) {
    (void)n_in; (void)out_size; (void)ws_size;
    const int N = in_sizes[0] / DFEAT;        // 50000
    const int E = in_sizes[4] / 2;            // 800000
    const int NC = in_sizes[15];              // 40

    const float* x1a = (const float*)d_in[0];
    const float* x1b = (const float*)d_in[1];
    const float* x2a = (const float*)d_in[2];
    const float* x2b = (const float*)d_in[3];
    const int* ei1 = (const int*)d_in[4];
    const int* ei2 = (const int*)d_in[5];
    const float* Wi = (const float*)d_in[6];
    const float* bi = (const float*)d_in[7];
    const float* gi = (const float*)d_in[8];
    const float* bei = (const float*)d_in[9];
    const float* Wm = (const float*)d_in[10];
    const float* bm = (const float*)d_in[11];
    const float* gm = (const float*)d_in[12];
    const float* bem = (const float*)d_in[13];
    const float* Wf = (const float*)d_in[14];
    const float* bf = (const float*)d_in[15];
    const float* fc1w1_W = (const float*)d_in[16];
    const float* fc1w1_b = (const float*)d_in[17];
    const float* fc1w2_W = (const float*)d_in[18];
    const float* fc1w2_b = (const float*)d_in[19];
    const float* aws_w1_W = (const float*)d_in[20];
    const float* aws_w1_b = (const float*)d_in[21];
    const float* aws_w2_W = (const float*)d_in[22];
    const float* aws_w2_b = (const float*)d_in[23];
    const float* fcw1_W = (const float*)d_in[24];
    const float* fcw1_b = (const float*)d_in[25];
    const float* fcw2_W = (const float*)d_in[26];
    const float* fcw2_b = (const float*)d_in[27];

    char* ws = (char*)d_ws;
    size_t off = 0;
    auto alloc = [&](size_t bytes) -> char* {
        char* p = ws + off;
        off += (bytes + 255) & ~(size_t)255;
        return p;
    };
    float* A = (float*)alloc((size_t)N * DFEAT * 4);   // pre-BN branch 1
    float* B = (float*)alloc((size_t)N * DFEAT * 4);   // pre-BN branch 2
    unsigned short* H1 = (unsigned short*)alloc((size_t)N * DFEAT * 2);  // bf16 staging
    unsigned short* H2 = (unsigned short*)alloc((size_t)N * DFEAT * 2);  // bf16 staging / P40
    int* rp1 = (int*)alloc((size_t)(N + 1) * 4);
    int* rp2 = (int*)alloc((size_t)(N + 1) * 4);
    int* cntb = (int*)alloc((size_t)2 * N * 4);
    int* cnt1 = cntb;
    int* cnt2 = cntb + N;
    int* flb = (int*)alloc((size_t)2 * N * 4);
    int* fl1 = flb;
    int* fl2 = flb + N;
    float* dv1 = (float*)alloc((size_t)N * 4);
    float* dv2 = (float*)alloc((size_t)N * 4);
    int* cs1 = (int*)alloc((size_t)E * 4);
    float* cn1 = (float*)alloc((size_t)E * 4);
    int* cs2 = (int*)alloc((size_t)E * 4);
    float* cn2 = (float*)alloc((size_t)E * 4);
    float* stats = (float*)alloc(2048);  // statsA(256) + statsB(256)
    float* statsA = stats;
    float* statsB = stats + 256;
    float* ssbuf = (float*)alloc(2048);
    float* wout = (float*)alloc(256);
    int nb = (N + 2047) / 2048;  // 25
    int* bsums = (int*)alloc((size_t)2 * nb * 4);

    const int* src1 = ei1;
    const int* dst1 = ei1 + E;
    const int* src2 = ei2;
    const int* dst2 = ei2 + E;

    int ebl = (E + 255) / 256;
    int gemmbl = (N + 63) / 64;
    dim3 agggrid((N * 32 + 255) / 256, 2);
    dim3 agggrid40((N * 16 + 255) / 256, 2);
    dim3 statgrid((N + 127) / 128, 2);
    dim3 scangrid(nb, 2);

    // ---- CSR build ----
    hipMemsetAsync(cntb, 0, (size_t)2 * N * 4, stream);
    hipMemsetAsync(flb, 0, (size_t)2 * N * 4, stream);
    count_kernel<<<ebl, 256, 0, stream>>>(dst1, cnt1, E);
    count_kernel<<<ebl, 256, 0, stream>>>(dst2, cnt2, E);
    blocksum_kernel<<<scangrid, 256, 0, stream>>>(cnt1, cnt2, bsums, N, nb);
    scansums_kernel<<<1, 64, 0, stream>>>(bsums, nb, rp1, rp2, N, E);
    writerp_kernel<<<scangrid, 256, 0, stream>>>(cnt1, cnt2, bsums, rp1, rp2, dv1, dv2, N, nb);
    fill_kernel<<<ebl, 256, 0, stream>>>(src1, dst1, rp1, fl1, cs1, cn1, dv1, E);
    fill_kernel<<<ebl, 256, 0, stream>>>(src2, dst2, rp2, fl2, cs2, cn2, dv2, E);

    // ---- Layer 1 ----
    gemm_kernel<16, 4, false><<<gemmbl, 256, 0, stream>>>(x1a, nullptr, nullptr, nullptr, Wi, H1,
                                                          N, 64, DFEAT, 0);
    gemm_kernel<16, 4, false><<<gemmbl, 256, 0, stream>>>(x1b, nullptr, nullptr, nullptr,
                                                          Wi + 128 * 64, H1, N, 64, DFEAT, 64);
    gemm_kernel<16, 4, false><<<gemmbl, 256, 0, stream>>>(x2a, nullptr, nullptr, nullptr, Wi, H2,
                                                          N, 64, DFEAT, 0);
    gemm_kernel<16, 4, false><<<gemmbl, 256, 0, stream>>>(x2b, nullptr, nullptr, nullptr,
                                                          Wi + 128 * 64, H2, N, 64, DFEAT, 64);
    dualagg_kernel<32, 32><<<agggrid, 256, 0, stream>>>(H1, H2, rp1, cs1, cn1, dv1, rp2, cs2, cn2,
                                                        dv2, bi, A, B, N);
    hipMemsetAsync(stats, 0, 2048, stream);
    stats2_kernel<<<statgrid, 256, 0, stream>>>(A, B, stats, N);
    gate_prep_kernel<<<1, 128, 0, stream>>>(statsA, statsB, A, B, gi, bei, fc1w1_W, fc1w1_b,
                                            fc1w2_W, fc1w2_b, ssbuf, wout, N);

    // ---- Middle layer 0 (combine fused into GEMM X-load) ----
    gemm_kernel<32, 8, true><<<gemmbl, 256, 0, stream>>>(A, B, ssbuf, wout, Wm, H1, N, 128, 128, 0);
    dualagg_kernel<32, 32><<<agggrid, 256, 0, stream>>>(H1, H1, rp1, cs1, cn1, dv1, rp2, cs2, cn2,
                                                        dv2, bm, A, B, N);
    hipMemsetAsync(stats, 0, 2048, stream);
    stats2_kernel<<<statgrid, 256, 0, stream>>>(A, B, stats, N);
    gate_prep_kernel<<<1, 128, 0, stream>>>(statsA, statsB, A, B, gm, bem, aws_w1_W, aws_w1_b,
                                            aws_w2_W, aws_w2_b, ssbuf, wout, N);

    // ---- Middle layer 1 ----
    gemm_kernel<32, 8, true><<<gemmbl, 256, 0, stream>>>(A, B, ssbuf, wout, Wm + 128 * 128, H1, N,
                                                         128, 128, 0);
    dualagg_kernel<32, 32><<<agggrid, 256, 0, stream>>>(H1, H1, rp1, cs1, cn1, dv1, rp2, cs2, cn2,
                                                        dv2, bm + 128, A, B, N);
    hipMemsetAsync(stats, 0, 2048, stream);
    stats2_kernel<<<statgrid, 256, 0, stream>>>(A, B, stats, N);
    gate_prep_kernel<<<1, 128, 0, stream>>>(statsA, statsB, A, B, gm + 128, bem + 128,
                                            aws_w1_W + 128, aws_w1_b + 1, aws_w2_W + 128,
                                            aws_w2_b + 1, ssbuf, wout, N);

    // ---- Final layer ----
    float* out0 = (float*)d_out;
    float* p1 = out0 + (size_t)N * NC;
    float* p2 = out0 + (size_t)2 * N * NC;
    gemm_kernel<16, 4, true><<<gemmbl, 256, 0, stream>>>(A, B, ssbuf, wout, Wf, H2, N, NC, NC, 0);
    dualagg_kernel<10, 16><<<agggrid40, 256, 0, stream>>>(H2, H2, rp1, cs1, cn1, dv1, rp2, cs2,
                                                          cn2, dv2, bf, p1, p2, N);
    gate_final_kernel<<<1, 64, 0, stream>>>(p1, p2, fcw1_W, fcw1_b, fcw2_W, fcw2_b, wout, N, NC);
    mix_kernel<<<(N * NC / 4 + 255) / 256, 256, 0, stream>>>(p1, p2, wout, out0, N * NC / 4);
}

// Round 6
// 827.746 us; speedup vs baseline: 1.4283x; 1.0287x over previous
//
#include <hip/hip_runtime.h>

// CLAGCN forward on MI355X.
// R1: stats 2-level. R2: multi-block scan. R3: bf16 staging + dual agg +
// fused combine. R4: revert stats to atomicAdd (gate_prep was serial).
// R5: (a) dualagg = one wave/node, half-wave edge split, unroll x4 (8
//     gathers in flight), int2 edge metadata; (b) A/B pre-BN buffers bf16
//     (halves agg writes, stats reads, fused-GEMM reads); (c) dispatch
//     count 31->22: quad layer-1 GEMM, dual count/fill, one zero-memset,
//     stats zeroing folded into scansums/gate_prep.

#define DFEAT 128

__device__ __forceinline__ unsigned short f2bf(float f) {
    unsigned u = __float_as_uint(f);
    u += 0x7fffu + ((u >> 16) & 1u);
    return (unsigned short)(u >> 16);
}
__device__ __forceinline__ float bf2f(unsigned short u) {
    return __uint_as_float((unsigned)u << 16);
}
__device__ __forceinline__ float4 bf4tof4(ushort4 u) {
    return make_float4(__uint_as_float((unsigned)u.x << 16),
                       __uint_as_float((unsigned)u.y << 16),
                       __uint_as_float((unsigned)u.z << 16),
                       __uint_as_float((unsigned)u.w << 16));
}

// ---------------- CSR build ----------------
__global__ void count_kernel(const int* __restrict__ dst1, const int* __restrict__ dst2,
                             int* __restrict__ cnt1, int* __restrict__ cnt2, int E) {
    int i = blockIdx.x * blockDim.x + threadIdx.x;
    if (i >= E) return;
    if (blockIdx.y == 0) atomicAdd(&cnt1[dst1[i]], 1);
    else                 atomicAdd(&cnt2[dst2[i]], 1);
}

__global__ __launch_bounds__(256) void blocksum_kernel(const int* __restrict__ c1,
                                                       const int* __restrict__ c2,
                                                       int* __restrict__ bs, int n, int nb) {
    const int* c = blockIdx.y ? c2 : c1;
    int* out = bs + (size_t)blockIdx.y * nb;
    int t = threadIdx.x;
    int base = blockIdx.x * 2048 + t * 8;
    int s = 0;
#pragma unroll
    for (int i = 0; i < 8; ++i) {
        int idx = base + i;
        if (idx < n) s += c[idx];
    }
    __shared__ int red[256];
    red[t] = s;
    __syncthreads();
    for (int o = 128; o > 0; o >>= 1) {
        if (t < o) red[t] += red[t + o];
        __syncthreads();
    }
    if (t == 0) out[blockIdx.x] = red[0];
}

// scan of per-block sums + zero the BN stats accumulator (512 floats).
__global__ void scansums_kernel(int* __restrict__ bs, int nb, int* __restrict__ rp1,
                                int* __restrict__ rp2, int n, int E, float* __restrict__ stats) {
    int t = threadIdx.x;  // 64 threads
    if (t < 2) {
        int* b = bs + (size_t)t * nb;
        int run = 0;
        for (int i = 0; i < nb; ++i) {
            int v = b[i];
            b[i] = run;
            run += v;
        }
        (t ? rp2 : rp1)[n] = E;
    }
    for (int i = t; i < 512; i += 64) stats[i] = 0.f;
}

__global__ __launch_bounds__(256) void writerp_kernel(const int* __restrict__ c1,
                                                      const int* __restrict__ c2,
                                                      const int* __restrict__ bs,
                                                      int* __restrict__ rp1, int* __restrict__ rp2,
                                                      float* __restrict__ dv1,
                                                      float* __restrict__ dv2, int n, int nb) {
    const int* c = blockIdx.y ? c2 : c1;
    int* rp = blockIdx.y ? rp2 : rp1;
    float* dv = blockIdx.y ? dv2 : dv1;
    int boff = bs[(size_t)blockIdx.y * nb + blockIdx.x];
    int t = threadIdx.x;
    int base = blockIdx.x * 2048 + t * 8;
    int v[8];
    int s = 0;
#pragma unroll
    for (int i = 0; i < 8; ++i) {
        int idx = base + i;
        v[i] = (idx < n) ? c[idx] : 0;
        s += v[i];
    }
    __shared__ int red[256];
    red[t] = s;
    __syncthreads();
    for (int o = 1; o < 256; o <<= 1) {
        int x = (t >= o) ? red[t - o] : 0;
        __syncthreads();
        red[t] += x;
        __syncthreads();
    }
    int run = boff + red[t] - s;
#pragma unroll
    for (int i = 0; i < 8; ++i) {
        int idx = base + i;
        if (idx < n) {
            rp[idx] = run;
            dv[idx] = rsqrtf((float)(v[i] + 1));  // +1 self-loop
            run += v[i];
        }
    }
}

// fill both graphs; edge metadata packed as int2 {src, norm_bits}
__global__ void fill_kernel(const int* __restrict__ src1, const int* __restrict__ dst1,
                            const int* __restrict__ src2, const int* __restrict__ dst2,
                            const int* __restrict__ rp1, const int* __restrict__ rp2,
                            int* __restrict__ fl1, int* __restrict__ fl2,
                            int2* __restrict__ ed1, int2* __restrict__ ed2,
                            const float* __restrict__ dv1, const float* __restrict__ dv2, int E) {
    int i = blockIdx.x * blockDim.x + threadIdx.x;
    if (i >= E) return;
    const int *src, *dst, *rp;
    int* fl;
    int2* ed;
    const float* dv;
    if (blockIdx.y == 0) { src = src1; dst = dst1; rp = rp1; fl = fl1; ed = ed1; dv = dv1; }
    else                 { src = src2; dst = dst2; rp = rp2; fl = fl2; ed = ed2; dv = dv2; }
    int d = dst[i];
    int s = src[i];
    int pos = rp[d] + atomicAdd(&fl[d], 1);
    ed[pos] = make_int2(s, __float_as_int(dv[s] * dv[d]));
}

// ---------------- dual aggregation: one wave per node ----------------
// lanes 0-31 take even edges, 32-63 odd edges; cross-half shfl reduce.
// h is bf16; OutT = unsigned short (bf16 staging) or float (final output).
template <int FV, typename OutT>
__global__ __launch_bounds__(256) void dualagg_kernel(
    const unsigned short* __restrict__ h1, const unsigned short* __restrict__ h2,
    const int* __restrict__ rp1, const int2* __restrict__ ed1, const float* __restrict__ dv1,
    const int* __restrict__ rp2, const int2* __restrict__ ed2, const float* __restrict__ dv2,
    const float* __restrict__ bias, OutT* __restrict__ o1, OutT* __restrict__ o2, int n) {
    constexpr int COLS = FV * 4;
    const unsigned short* h;
    const int* rp;
    const int2* ed;
    const float* dv;
    OutT* out;
    if (blockIdx.y == 0) { h = h1; rp = rp1; ed = ed1; dv = dv1; out = o1; }
    else                 { h = h2; rp = rp2; ed = ed2; dv = dv2; out = o2; }
    int wid = blockIdx.x * 4 + (threadIdx.x >> 6);
    if (wid >= n) return;
    int lane = threadIdx.x & 63;
    int half = lane >> 5;
    int l = lane & 31;
    bool act = (l < FV);
    float4 acc = make_float4(0.f, 0.f, 0.f, 0.f);
    int e0 = rp[wid], e1 = rp[wid + 1];
    int e = e0 + half;
    for (; e + 6 < e1; e += 8) {
        int2 ea = ed[e], eb = ed[e + 2], ec = ed[e + 4], eD = ed[e + 6];
        if (act) {
            float4 ha = bf4tof4(((const ushort4*)(h + (size_t)ea.x * COLS))[l]);
            float4 hb = bf4tof4(((const ushort4*)(h + (size_t)eb.x * COLS))[l]);
            float4 hc = bf4tof4(((const ushort4*)(h + (size_t)ec.x * COLS))[l]);
            float4 hd = bf4tof4(((const ushort4*)(h + (size_t)eD.x * COLS))[l]);
            float wa = __int_as_float(ea.y), wb = __int_as_float(eb.y);
            float wc = __int_as_float(ec.y), wd = __int_as_float(eD.y);
            acc.x = fmaf(wa, ha.x, acc.x); acc.y = fmaf(wa, ha.y, acc.y);
            acc.z = fmaf(wa, ha.z, acc.z); acc.w = fmaf(wa, ha.w, acc.w);
            acc.x = fmaf(wb, hb.x, acc.x); acc.y = fmaf(wb, hb.y, acc.y);
            acc.z = fmaf(wb, hb.z, acc.z); acc.w = fmaf(wb, hb.w, acc.w);
            acc.x = fmaf(wc, hc.x, acc.x); acc.y = fmaf(wc, hc.y, acc.y);
            acc.z = fmaf(wc, hc.z, acc.z); acc.w = fmaf(wc, hc.w, acc.w);
            acc.x = fmaf(wd, hd.x, acc.x); acc.y = fmaf(wd, hd.y, acc.y);
            acc.z = fmaf(wd, hd.z, acc.z); acc.w = fmaf(wd, hd.w, acc.w);
        }
    }
    for (; e < e1; e += 2) {
        int2 ea = ed[e];
        if (act) {
            float4 ha = bf4tof4(((const ushort4*)(h + (size_t)ea.x * COLS))[l]);
            float wa = __int_as_float(ea.y);
            acc.x = fmaf(wa, ha.x, acc.x); acc.y = fmaf(wa, ha.y, acc.y);
            acc.z = fmaf(wa, ha.z, acc.z); acc.w = fmaf(wa, ha.w, acc.w);
        }
    }
    // cross-half reduce
    acc.x += __shfl_xor(acc.x, 32);
    acc.y += __shfl_xor(acc.y, 32);
    acc.z += __shfl_xor(acc.z, 32);
    acc.w += __shfl_xor(acc.w, 32);
    if (half == 0 && act) {
        float dn = dv[wid];
        float w = dn * dn;  // self-loop norm
        float4 hv = bf4tof4(((const ushort4*)(h + (size_t)wid * COLS))[l]);
        acc.x = fmaf(w, hv.x, acc.x); acc.y = fmaf(w, hv.y, acc.y);
        acc.z = fmaf(w, hv.z, acc.z); acc.w = fmaf(w, hv.w, acc.w);
        float4 b = ((const float4*)bias)[l];
        acc.x += b.x; acc.y += b.y; acc.z += b.z; acc.w += b.w;
        if constexpr (sizeof(OutT) == 4) {
            ((float4*)((float*)out + (size_t)wid * COLS))[l] = acc;
        } else {
            ushort4 o;
            o.x = f2bf(acc.x); o.y = f2bf(acc.y); o.z = f2bf(acc.z); o.w = f2bf(acc.w);
            ((ushort4*)((unsigned short*)out + (size_t)wid * COLS))[l] = o;
        }
    }
}

// ---------------- Layer-1 quad GEMM: 4 (input, W-half) pairs in grid.y ----------------
__global__ __launch_bounds__(256) void gemm_l1_kernel(
    const float* __restrict__ x1a, const float* __restrict__ x1b, const float* __restrict__ x2a,
    const float* __restrict__ x2b, const float* __restrict__ Wi, unsigned short* __restrict__ H1,
    unsigned short* __restrict__ H2, int nrows) {
    constexpr int CG = 16;
    const float* X = (blockIdx.y == 0) ? x1a : (blockIdx.y == 1) ? x1b
                     : (blockIdx.y == 2) ? x2a : x2b;
    const float* W = Wi + (blockIdx.y & 1) * 128 * 64;
    unsigned short* Y = (blockIdx.y < 2) ? H1 : H2;
    int ocol = (int)(blockIdx.y & 1) * 64;
    __shared__ float Ws[32][64];
    __shared__ float Xs[64][32];
    int tid = threadIdx.x;
    int row0 = blockIdx.x * 64;
    int cg = tid % CG;
    int rg = tid / CG;
    float4 acc[4];
#pragma unroll
    for (int i = 0; i < 4; ++i) acc[i] = make_float4(0.f, 0.f, 0.f, 0.f);
    for (int kc = 0; kc < 4; ++kc) {
        for (int i = tid; i < 32 * CG; i += 256) {
            int r = i / CG, c = i % CG;
            *(float4*)&Ws[r][c * 4] = *(const float4*)(W + (size_t)(kc * 32 + r) * 64 + c * 4);
        }
        for (int i = tid; i < 64 * 8; i += 256) {
            int r = i / 8, c = i % 8;
            int gr = row0 + r;
            float4 v = make_float4(0.f, 0.f, 0.f, 0.f);
            if (gr < nrows) v = *(const float4*)(X + (size_t)gr * DFEAT + kc * 32 + c * 4);
            *(float4*)&Xs[r][c * 4] = v;
        }
        __syncthreads();
#pragma unroll
        for (int k = 0; k < 32; ++k) {
            float4 w = *(float4*)&Ws[k][cg * 4];
#pragma unroll
            for (int i = 0; i < 4; ++i) {
                float a = Xs[rg * 4 + i][k];
                acc[i].x = fmaf(a, w.x, acc[i].x);
                acc[i].y = fmaf(a, w.y, acc[i].y);
                acc[i].z = fmaf(a, w.z, acc[i].z);
                acc[i].w = fmaf(a, w.w, acc[i].w);
            }
        }
        __syncthreads();
    }
#pragma unroll
    for (int i = 0; i < 4; ++i) {
        int r = row0 + rg * 4 + i;
        if (r < nrows) {
            ushort4 o;
            o.x = f2bf(acc[i].x); o.y = f2bf(acc[i].y);
            o.z = f2bf(acc[i].z); o.w = f2bf(acc[i].w);
            *(ushort4*)(Y + (size_t)r * DFEAT + ocol + cg * 4) = o;
        }
    }
}

// ---------------- fused GEMM: x = w1*relu(bn(A)) + w2*relu(bn(B)), A/B bf16 ----------------
template <int CG, int RPT>
__global__ __launch_bounds__(256) void gemm_fused_kernel(
    const unsigned short* __restrict__ Abf, const unsigned short* __restrict__ Bbf,
    const float* __restrict__ ss, const float* __restrict__ wout, const float* __restrict__ W,
    unsigned short* __restrict__ Y, int nrows, int fout, int ostride) {
    __shared__ float Ws[32][CG * 4];
    __shared__ float Xs[64][32];
    int tid = threadIdx.x;
    int row0 = blockIdx.x * 64;
    int cg = tid % CG;
    int rg = tid / CG;
    float w1 = wout[0], w2 = wout[1];
    float4 acc[RPT];
#pragma unroll
    for (int i = 0; i < RPT; ++i) acc[i] = make_float4(0.f, 0.f, 0.f, 0.f);
    for (int kc = 0; kc < 4; ++kc) {
        for (int i = tid; i < 32 * CG; i += 256) {
            int r = i / CG, c = i % CG;
            float4 w;
            if ((c * 4 + 3) < fout) {
                w = *(const float4*)(W + (size_t)(kc * 32 + r) * fout + c * 4);
            } else {
                float t0 = (c * 4 + 0) < fout ? W[(size_t)(kc * 32 + r) * fout + c * 4 + 0] : 0.f;
                float t1 = (c * 4 + 1) < fout ? W[(size_t)(kc * 32 + r) * fout + c * 4 + 1] : 0.f;
                float t2 = (c * 4 + 2) < fout ? W[(size_t)(kc * 32 + r) * fout + c * 4 + 2] : 0.f;
                float t3 = (c * 4 + 3) < fout ? W[(size_t)(kc * 32 + r) * fout + c * 4 + 3] : 0.f;
                w = make_float4(t0, t1, t2, t3);
            }
            *(float4*)&Ws[r][c * 4] = w;
        }
        for (int i = tid; i < 64 * 8; i += 256) {
            int r = i / 8, c = i % 8;
            int gr = row0 + r;
            int col0 = kc * 32 + c * 4;
            float4 v = make_float4(0.f, 0.f, 0.f, 0.f);
            if (gr < nrows) {
                float4 a = bf4tof4(*(const ushort4*)(Abf + (size_t)gr * DFEAT + col0));
                float4 b = bf4tof4(*(const ushort4*)(Bbf + (size_t)gr * DFEAT + col0));
                float4 scA = *(const float4*)(ss + col0);
                float4 shA = *(const float4*)(ss + DFEAT + col0);
                float4 scB = *(const float4*)(ss + 2 * DFEAT + col0);
                float4 shB = *(const float4*)(ss + 3 * DFEAT + col0);
                v.x = w1 * fmaxf(fmaf(a.x, scA.x, shA.x), 0.f) +
                      w2 * fmaxf(fmaf(b.x, scB.x, shB.x), 0.f);
                v.y = w1 * fmaxf(fmaf(a.y, scA.y, shA.y), 0.f) +
                      w2 * fmaxf(fmaf(b.y, scB.y, shB.y), 0.f);
                v.z = w1 * fmaxf(fmaf(a.z, scA.z, shA.z), 0.f) +
                      w2 * fmaxf(fmaf(b.z, scB.z, shB.z), 0.f);
                v.w = w1 * fmaxf(fmaf(a.w, scA.w, shA.w), 0.f) +
                      w2 * fmaxf(fmaf(b.w, scB.w, shB.w), 0.f);
            }
            *(float4*)&Xs[r][c * 4] = v;
        }
        __syncthreads();
#pragma unroll
        for (int k = 0; k < 32; ++k) {
            float4 w = *(float4*)&Ws[k][cg * 4];
#pragma unroll
            for (int i = 0; i < RPT; ++i) {
                float a = Xs[rg * RPT + i][k];
                acc[i].x = fmaf(a, w.x, acc[i].x);
                acc[i].y = fmaf(a, w.y, acc[i].y);
                acc[i].z = fmaf(a, w.z, acc[i].z);
                acc[i].w = fmaf(a, w.w, acc[i].w);
            }
        }
        __syncthreads();
    }
    if (cg * 4 < fout) {
#pragma unroll
        for (int i = 0; i < RPT; ++i) {
            int r = row0 + rg * RPT + i;
            if (r < nrows) {
                ushort4 o;
                o.x = f2bf(acc[i].x); o.y = f2bf(acc[i].y);
                o.z = f2bf(acc[i].z); o.w = f2bf(acc[i].w);
                *(ushort4*)(Y + (size_t)r * ostride + cg * 4) = o;
            }
        }
    }
}

// ---------------- BN statistics from bf16 A/B: 2-level atomicAdd ----------------
__global__ __launch_bounds__(256) void stats2_kernel(const unsigned short* __restrict__ A,
                                                     const unsigned short* __restrict__ B,
                                                     float* __restrict__ stats, int nrows) {
    __shared__ float red1[256];
    __shared__ float red2[256];
    int t = threadIdx.x;
    int col = t & 127;
    int rg = t >> 7;
    const unsigned short* src = (blockIdx.y == 0) ? A : B;
    float* st = stats + (size_t)blockIdx.y * 256;
    int r0 = blockIdx.x * 128 + rg * 64;
    int r1 = min(r0 + 64, nrows);
    float s = 0.f, s2 = 0.f;
    for (int r = r0; r < r1; ++r) {
        float v = bf2f(src[(size_t)r * DFEAT + col]);
        s += v;
        s2 = fmaf(v, v, s2);
    }
    red1[t] = s;
    red2[t] = s2;
    __syncthreads();
    if (t < 128) {
        atomicAdd(&st[col], red1[t] + red1[t + 128]);
        atomicAdd(&st[DFEAT + col], red2[t] + red2[t + 128]);
    }
}

// ---------------- BN scale/shift + gates; zeros stats for next layer ----------------
__global__ __launch_bounds__(128) void gate_prep_kernel(
    float* __restrict__ statsA, float* __restrict__ statsB,
    const unsigned short* __restrict__ preA, const unsigned short* __restrict__ preB,
    const float* __restrict__ gamma, const float* __restrict__ beta,
    const float* __restrict__ gwA, const float* __restrict__ gbA,
    const float* __restrict__ gwB, const float* __restrict__ gbB,
    float* __restrict__ ss, float* __restrict__ wout, int nrows) {
    __shared__ float red[128];
    __shared__ float dotA_s;
    int t = threadIdx.x;
    float invN = 1.f / (float)nrows;
    float meanA = statsA[t] * invN;
    float varA = statsA[DFEAT + t] * invN - meanA * meanA;
    float scA = gamma[t] * rsqrtf(varA + 1e-5f);
    float shA = beta[t] - meanA * scA;
    ss[t] = scA;
    ss[DFEAT + t] = shA;
    float meanB = statsB[t] * invN;
    float varB = statsB[DFEAT + t] * invN - meanB * meanB;
    float scB = gamma[t] * rsqrtf(varB + 1e-5f);
    float shB = beta[t] - meanB * scB;
    ss[2 * DFEAT + t] = scB;
    ss[3 * DFEAT + t] = shB;
    statsA[t] = 0.f;
    statsA[DFEAT + t] = 0.f;
    statsB[t] = 0.f;
    statsB[DFEAT + t] = 0.f;
    float av = fmaxf(fmaf(bf2f(preA[(size_t)(nrows - 1) * DFEAT + t]), scA, shA), 0.f);
    red[t] = av * gwA[t];
    __syncthreads();
    for (int s = 64; s > 0; s >>= 1) {
        if (t < s) red[t] += red[t + s];
        __syncthreads();
    }
    if (t == 0) dotA_s = red[0];
    __syncthreads();
    float bv = fmaxf(fmaf(bf2f(preB[(size_t)(nrows - 1) * DFEAT + t]), scB, shB), 0.f);
    red[t] = bv * gwB[t];
    __syncthreads();
    for (int s = 64; s > 0; s >>= 1) {
        if (t < s) red[t] += red[t + s];
        __syncthreads();
    }
    if (t == 0) {
        float s1 = 1.f / (1.f + expf(-(dotA_s + gbA[0])));
        float s2 = 1.f / (1.f + expf(-(red[0] + gbB[0])));
        float tt = s1 + s2;
        wout[0] = s1 / tt;
        wout[1] = s2 / tt;
    }
}

__global__ __launch_bounds__(64) void gate_final_kernel(
    const float* __restrict__ p1, const float* __restrict__ p2,
    const float* __restrict__ w1v, const float* __restrict__ b1,
    const float* __restrict__ w2v, const float* __restrict__ b2,
    float* __restrict__ wout, int nrows, int nclass) {
    __shared__ float red[64];
    __shared__ float dot1_s;
    int t = threadIdx.x;
    float v = (t < nclass) ? p1[(size_t)(nrows - 1) * nclass + t] * w1v[t] : 0.f;
    red[t] = v;
    __syncthreads();
    for (int s = 32; s > 0; s >>= 1) {
        if (t < s) red[t] += red[t + s];
        __syncthreads();
    }
    if (t == 0) dot1_s = red[0];
    __syncthreads();
    v = (t < nclass) ? p2[(size_t)(nrows - 1) * nclass + t] * w2v[t] : 0.f;
    red[t] = v;
    __syncthreads();
    for (int s = 32; s > 0; s >>= 1) {
        if (t < s) red[t] += red[t + s];
        __syncthreads();
    }
    if (t == 0) {
        float s1 = 1.f / (1.f + expf(-(dot1_s + b1[0])));
        float s2 = 1.f / (1.f + expf(-(red[0] + b2[0])));
        float tt = s1 + s2;
        wout[0] = s1 / tt;
        wout[1] = s2 / tt;
    }
}

__global__ __launch_bounds__(256) void mix_kernel(const float* __restrict__ p1,
                                                  const float* __restrict__ p2,
                                                  const float* __restrict__ wout,
                                                  float* __restrict__ o, int n4) {
    int idx = blockIdx.x * blockDim.x + threadIdx.x;
    if (idx >= n4) return;
    float w1 = wout[0], w2 = wout[1];
    float4 a = *(const float4*)(p1 + (size_t)idx * 4);
    float4 b = *(const float4*)(p2 + (size_t)idx * 4);
    float4 r = make_float4(w1 * a.x + w2 * b.x, w1 * a.y + w2 * b.y, w1 * a.z + w2 * b.z,
                           w1 * a.w + w2 * b.w);
    *(float4*)(o + (size_t)idx * 4) = r;
}

extern "C" void kernel_launch(void* const* d_in, const int* in_sizes, int n_in, void* d_out,
                              int out_size, void* d_ws, size_t ws_size, hipStream_t stream) {
    (void)n_in; (void)out_size; (void)ws_size;
    const int N = in_sizes[0] / DFEAT;        // 50000
    const int E = in_sizes[4] / 2;            // 800000
    const int NC = in_sizes[15];              // 40

    const float* x1a = (const float*)d_in[0];
    const float* x1b = (const float*)d_in[1];
    const float* x2a = (const float*)d_in[2];
    const float* x2b = (const float*)d_in[3];
    const int* ei1 = (const int*)d_in[4];
    const int* ei2 = (const int*)d_in[5];
    const float* Wi = (const float*)d_in[6];
    const float* bi = (const float*)d_in[7];
    const float* gi = (const float*)d_in[8];
    const float* bei = (const float*)d_in[9];
    const float* Wm = (const float*)d_in[10];
    const float* bm = (const float*)d_in[11];
    const float* gm = (const float*)d_in[12];
    const float* bem = (const float*)d_in[13];
    const float* Wf = (const float*)d_in[14];
    const float* bf = (const float*)d_in[15];
    const float* fc1w1_W = (const float*)d_in[16];
    const float* fc1w1_b = (const float*)d_in[17];
    const float* fc1w2_W = (const float*)d_in[18];
    const float* fc1w2_b = (const float*)d_in[19];
    const float* aws_w1_W = (const float*)d_in[20];
    const float* aws_w1_b = (const float*)d_in[21];
    const float* aws_w2_W = (const float*)d_in[22];
    const float* aws_w2_b = (const float*)d_in[23];
    const float* fcw1_W = (const float*)d_in[24];
    const float* fcw1_b = (const float*)d_in[25];
    const float* fcw2_W = (const float*)d_in[26];
    const float* fcw2_b = (const float*)d_in[27];

    char* ws = (char*)d_ws;
    size_t off = 0;
    auto alloc = [&](size_t bytes) -> char* {
        char* p = ws + off;
        off += (bytes + 255) & ~(size_t)255;
        return p;
    };
    unsigned short* A = (unsigned short*)alloc((size_t)N * DFEAT * 2);   // pre-BN branch 1 (bf16)
    unsigned short* B = (unsigned short*)alloc((size_t)N * DFEAT * 2);   // pre-BN branch 2 (bf16)
    unsigned short* H1 = (unsigned short*)alloc((size_t)N * DFEAT * 2);  // bf16 staging
    unsigned short* H2 = (unsigned short*)alloc((size_t)N * DFEAT * 2);  // bf16 staging / P40
    int* rp1 = (int*)alloc((size_t)(N + 1) * 4);
    int* rp2 = (int*)alloc((size_t)(N + 1) * 4);
    int* zb = (int*)alloc((size_t)4 * N * 4);  // cnt1|cnt2|fl1|fl2 — one memset
    int* cnt1 = zb;
    int* cnt2 = zb + N;
    int* fl1 = zb + 2 * N;
    int* fl2 = zb + 3 * N;
    float* dv1 = (float*)alloc((size_t)N * 4);
    float* dv2 = (float*)alloc((size_t)N * 4);
    int2* ed1 = (int2*)alloc((size_t)E * 8);
    int2* ed2 = (int2*)alloc((size_t)E * 8);
    float* stats = (float*)alloc(2048);  // statsA(256)+statsB(256)
    float* statsA = stats;
    float* statsB = stats + 256;
    float* ssbuf = (float*)alloc(2048);
    float* wout = (float*)alloc(256);
    int nb = (N + 2047) / 2048;  // 25
    int* bsums = (int*)alloc((size_t)2 * nb * 4);

    const int* src1 = ei1;
    const int* dst1 = ei1 + E;
    const int* src2 = ei2;
    const int* dst2 = ei2 + E;

    int ebl = (E + 255) / 256;
    int gemmbl = (N + 63) / 64;
    dim3 dualgrid(ebl, 2);
    dim3 agggrid((N + 3) / 4, 2);
    dim3 statgrid((N + 127) / 128, 2);
    dim3 scangrid(nb, 2);
    dim3 l1grid(gemmbl, 4);

    // ---- CSR build ----
    hipMemsetAsync(zb, 0, (size_t)4 * N * 4, stream);
    count_kernel<<<dualgrid, 256, 0, stream>>>(dst1, dst2, cnt1, cnt2, E);
    blocksum_kernel<<<scangrid, 256, 0, stream>>>(cnt1, cnt2, bsums, N, nb);
    scansums_kernel<<<1, 64, 0, stream>>>(bsums, nb, rp1, rp2, N, E, stats);
    writerp_kernel<<<scangrid, 256, 0, stream>>>(cnt1, cnt2, bsums, rp1, rp2, dv1, dv2, N, nb);
    fill_kernel<<<dualgrid, 256, 0, stream>>>(src1, dst1, src2, dst2, rp1, rp2, fl1, fl2, ed1,
                                              ed2, dv1, dv2, E);

    // ---- Layer 1 ----
    gemm_l1_kernel<<<l1grid, 256, 0, stream>>>(x1a, x1b, x2a, x2b, Wi, H1, H2, N);
    dualagg_kernel<32, unsigned short><<<agggrid, 256, 0, stream>>>(
        H1, H2, rp1, ed1, dv1, rp2, ed2, dv2, bi, A, B, N);
    stats2_kernel<<<statgrid, 256, 0, stream>>>(A, B, stats, N);
    gate_prep_kernel<<<1, 128, 0, stream>>>(statsA, statsB, A, B, gi, bei, fc1w1_W, fc1w1_b,
                                            fc1w2_W, fc1w2_b, ssbuf, wout, N);

    // ---- Middle layer 0 ----
    gemm_fused_kernel<32, 8><<<gemmbl, 256, 0, stream>>>(A, B, ssbuf, wout, Wm, H1, N, 128, 128);
    dualagg_kernel<32, unsigned short><<<agggrid, 256, 0, stream>>>(
        H1, H1, rp1, ed1, dv1, rp2, ed2, dv2, bm, A, B, N);
    stats2_kernel<<<statgrid, 256, 0, stream>>>(A, B, stats, N);
    gate_prep_kernel<<<1, 128, 0, stream>>>(statsA, statsB, A, B, gm, bem, aws_w1_W, aws_w1_b,
                                            aws_w2_W, aws_w2_b, ssbuf, wout, N);

    // ---- Middle layer 1 ----
    gemm_fused_kernel<32, 8><<<gemmbl, 256, 0, stream>>>(A, B, ssbuf, wout, Wm + 128 * 128, H1, N,
                                                         128, 128);
    dualagg_kernel<32, unsigned short><<<agggrid, 256, 0, stream>>>(
        H1, H1, rp1, ed1, dv1, rp2, ed2, dv2, bm + 128, A, B, N);
    stats2_kernel<<<statgrid, 256, 0, stream>>>(A, B, stats, N);
    gate_prep_kernel<<<1, 128, 0, stream>>>(statsA, statsB, A, B, gm + 128, bem + 128,
                                            aws_w1_W + 128, aws_w1_b + 1, aws_w2_W + 128,
                                            aws_w2_b + 1, ssbuf, wout, N);

    // ---- Final layer ----
    float* out0 = (float*)d_out;
    float* p1 = out0 + (size_t)N * NC;
    float* p2 = out0 + (size_t)2 * N * NC;
    gemm_fused_kernel<16, 4><<<gemmbl, 256, 0, stream>>>(A, B, ssbuf, wout, Wf, H2, N, NC, NC);
    dualagg_kernel<10, float><<<agggrid, 256, 0, stream>>>(H2, H2, rp1, ed1, dv1, rp2, ed2, dv2,
                                                           bf, p1, p2, N);
    gate_final_kernel<<<1, 64, 0, stream>>>(p1, p2, fcw1_W, fcw1_b, fcw2_W, fcw2_b, wout, N, NC);
    mix_kernel<<<(N * NC / 4 + 255) / 256, 256, 0, stream>>>(p1, p2, wout, out0, N * NC / 4);
}

// Round 7
// 809.495 us; speedup vs baseline: 1.4605x; 1.0225x over previous
//
#include <hip/hip_runtime.h>

// CLAGCN forward on MI355X.
// R1: stats 2-level. R2: multi-block scan. R3: bf16 staging + dual agg +
// fused combine. R4: revert stats to atomicAdd. R5: wave/node agg, bf16 A/B,
// fewer dispatches.
// R6: (a) fill scatter payload 8B->4B (src only; agg computes norm from dv —
//     fill had 8x write amplification, 106MB for 12.8MB payload);
//     (b) middle 128x128 fused GEMMs -> MFMA bf16 (prepW pre-transposes Wm
//     to bf16 [kc][col][32] so B-frags are coalesced 1KB L2-hot reads).

#define DFEAT 128

typedef __attribute__((ext_vector_type(8))) short bf16x8;
typedef __attribute__((ext_vector_type(4))) float f32x4;

__device__ __forceinline__ unsigned short f2bf(float f) {
    unsigned u = __float_as_uint(f);
    u += 0x7fffu + ((u >> 16) & 1u);
    return (unsigned short)(u >> 16);
}
__device__ __forceinline__ float bf2f(unsigned short u) {
    return __uint_as_float((unsigned)u << 16);
}
__device__ __forceinline__ float4 bf4tof4(ushort4 u) {
    return make_float4(__uint_as_float((unsigned)u.x << 16),
                       __uint_as_float((unsigned)u.y << 16),
                       __uint_as_float((unsigned)u.z << 16),
                       __uint_as_float((unsigned)u.w << 16));
}

// ---------------- CSR build ----------------
__global__ void count_kernel(const int* __restrict__ dst1, const int* __restrict__ dst2,
                             int* __restrict__ cnt1, int* __restrict__ cnt2, int E) {
    int i = blockIdx.x * blockDim.x + threadIdx.x;
    if (i >= E) return;
    if (blockIdx.y == 0) atomicAdd(&cnt1[dst1[i]], 1);
    else                 atomicAdd(&cnt2[dst2[i]], 1);
}

__global__ __launch_bounds__(256) void blocksum_kernel(const int* __restrict__ c1,
                                                       const int* __restrict__ c2,
                                                       int* __restrict__ bs, int n, int nb) {
    const int* c = blockIdx.y ? c2 : c1;
    int* out = bs + (size_t)blockIdx.y * nb;
    int t = threadIdx.x;
    int base = blockIdx.x * 2048 + t * 8;
    int s = 0;
#pragma unroll
    for (int i = 0; i < 8; ++i) {
        int idx = base + i;
        if (idx < n) s += c[idx];
    }
    __shared__ int red[256];
    red[t] = s;
    __syncthreads();
    for (int o = 128; o > 0; o >>= 1) {
        if (t < o) red[t] += red[t + o];
        __syncthreads();
    }
    if (t == 0) out[blockIdx.x] = red[0];
}

__global__ void scansums_kernel(int* __restrict__ bs, int nb, int* __restrict__ rp1,
                                int* __restrict__ rp2, int n, int E, float* __restrict__ stats) {
    int t = threadIdx.x;  // 64 threads
    if (t < 2) {
        int* b = bs + (size_t)t * nb;
        int run = 0;
        for (int i = 0; i < nb; ++i) {
            int v = b[i];
            b[i] = run;
            run += v;
        }
        (t ? rp2 : rp1)[n] = E;
    }
    for (int i = t; i < 512; i += 64) stats[i] = 0.f;
}

__global__ __launch_bounds__(256) void writerp_kernel(const int* __restrict__ c1,
                                                      const int* __restrict__ c2,
                                                      const int* __restrict__ bs,
                                                      int* __restrict__ rp1, int* __restrict__ rp2,
                                                      float* __restrict__ dv1,
                                                      float* __restrict__ dv2, int n, int nb) {
    const int* c = blockIdx.y ? c2 : c1;
    int* rp = blockIdx.y ? rp2 : rp1;
    float* dv = blockIdx.y ? dv2 : dv1;
    int boff = bs[(size_t)blockIdx.y * nb + blockIdx.x];
    int t = threadIdx.x;
    int base = blockIdx.x * 2048 + t * 8;
    int v[8];
    int s = 0;
#pragma unroll
    for (int i = 0; i < 8; ++i) {
        int idx = base + i;
        v[i] = (idx < n) ? c[idx] : 0;
        s += v[i];
    }
    __shared__ int red[256];
    red[t] = s;
    __syncthreads();
    for (int o = 1; o < 256; o <<= 1) {
        int x = (t >= o) ? red[t - o] : 0;
        __syncthreads();
        red[t] += x;
        __syncthreads();
    }
    int run = boff + red[t] - s;
#pragma unroll
    for (int i = 0; i < 8; ++i) {
        int idx = base + i;
        if (idx < n) {
            rp[idx] = run;
            dv[idx] = rsqrtf((float)(v[i] + 1));  // +1 self-loop
            run += v[i];
        }
    }
}

// fill: 4-byte payload (src only) — norm computed in agg from dv.
__global__ void fill_kernel(const int* __restrict__ src1, const int* __restrict__ dst1,
                            const int* __restrict__ src2, const int* __restrict__ dst2,
                            const int* __restrict__ rp1, const int* __restrict__ rp2,
                            int* __restrict__ fl1, int* __restrict__ fl2,
                            int* __restrict__ cs1, int* __restrict__ cs2, int E) {
    int i = blockIdx.x * blockDim.x + threadIdx.x;
    if (i >= E) return;
    const int *src, *dst, *rp;
    int *fl, *cs;
    if (blockIdx.y == 0) { src = src1; dst = dst1; rp = rp1; fl = fl1; cs = cs1; }
    else                 { src = src2; dst = dst2; rp = rp2; fl = fl2; cs = cs2; }
    int d = dst[i];
    int pos = rp[d] + atomicAdd(&fl[d], 1);
    cs[pos] = src[i];
}

// ---------------- dual aggregation: one wave per node ----------------
template <int FV, typename OutT>
__global__ __launch_bounds__(256) void dualagg_kernel(
    const unsigned short* __restrict__ h1, const unsigned short* __restrict__ h2,
    const int* __restrict__ rp1, const int* __restrict__ cs1, const float* __restrict__ dv1,
    const int* __restrict__ rp2, const int* __restrict__ cs2, const float* __restrict__ dv2,
    const float* __restrict__ bias, OutT* __restrict__ o1, OutT* __restrict__ o2, int n) {
    constexpr int COLS = FV * 4;
    const unsigned short* h;
    const int *rp, *cs;
    const float* dv;
    OutT* out;
    if (blockIdx.y == 0) { h = h1; rp = rp1; cs = cs1; dv = dv1; out = o1; }
    else                 { h = h2; rp = rp2; cs = cs2; dv = dv2; out = o2; }
    int wid = blockIdx.x * 4 + (threadIdx.x >> 6);
    if (wid >= n) return;
    int lane = threadIdx.x & 63;
    int half = lane >> 5;
    int l = lane & 31;
    bool act = (l < FV);
    float dn = dv[wid];
    float4 acc = make_float4(0.f, 0.f, 0.f, 0.f);
    int e0 = rp[wid], e1 = rp[wid + 1];
    int e = e0 + half;
    for (; e + 6 < e1; e += 8) {
        int sa = cs[e], sb = cs[e + 2], sc = cs[e + 4], sd = cs[e + 6];
        float wa = dv[sa] * dn, wb = dv[sb] * dn, wc = dv[sc] * dn, wd = dv[sd] * dn;
        if (act) {
            float4 ha = bf4tof4(((const ushort4*)(h + (size_t)sa * COLS))[l]);
            float4 hb = bf4tof4(((const ushort4*)(h + (size_t)sb * COLS))[l]);
            float4 hc = bf4tof4(((const ushort4*)(h + (size_t)sc * COLS))[l]);
            float4 hd = bf4tof4(((const ushort4*)(h + (size_t)sd * COLS))[l]);
            acc.x = fmaf(wa, ha.x, acc.x); acc.y = fmaf(wa, ha.y, acc.y);
            acc.z = fmaf(wa, ha.z, acc.z); acc.w = fmaf(wa, ha.w, acc.w);
            acc.x = fmaf(wb, hb.x, acc.x); acc.y = fmaf(wb, hb.y, acc.y);
            acc.z = fmaf(wb, hb.z, acc.z); acc.w = fmaf(wb, hb.w, acc.w);
            acc.x = fmaf(wc, hc.x, acc.x); acc.y = fmaf(wc, hc.y, acc.y);
            acc.z = fmaf(wc, hc.z, acc.z); acc.w = fmaf(wc, hc.w, acc.w);
            acc.x = fmaf(wd, hd.x, acc.x); acc.y = fmaf(wd, hd.y, acc.y);
            acc.z = fmaf(wd, hd.z, acc.z); acc.w = fmaf(wd, hd.w, acc.w);
        }
    }
    for (; e < e1; e += 2) {
        int sa = cs[e];
        float wa = dv[sa] * dn;
        if (act) {
            float4 ha = bf4tof4(((const ushort4*)(h + (size_t)sa * COLS))[l]);
            acc.x = fmaf(wa, ha.x, acc.x); acc.y = fmaf(wa, ha.y, acc.y);
            acc.z = fmaf(wa, ha.z, acc.z); acc.w = fmaf(wa, ha.w, acc.w);
        }
    }
    acc.x += __shfl_xor(acc.x, 32);
    acc.y += __shfl_xor(acc.y, 32);
    acc.z += __shfl_xor(acc.z, 32);
    acc.w += __shfl_xor(acc.w, 32);
    if (half == 0 && act) {
        float w = dn * dn;  // self-loop norm
        float4 hv = bf4tof4(((const ushort4*)(h + (size_t)wid * COLS))[l]);
        acc.x = fmaf(w, hv.x, acc.x); acc.y = fmaf(w, hv.y, acc.y);
        acc.z = fmaf(w, hv.z, acc.z); acc.w = fmaf(w, hv.w, acc.w);
        float4 b = ((const float4*)bias)[l];
        acc.x += b.x; acc.y += b.y; acc.z += b.z; acc.w += b.w;
        if constexpr (sizeof(OutT) == 4) {
            ((float4*)((float*)out + (size_t)wid * COLS))[l] = acc;
        } else {
            ushort4 o;
            o.x = f2bf(acc.x); o.y = f2bf(acc.y); o.z = f2bf(acc.z); o.w = f2bf(acc.w);
            ((ushort4*)((unsigned short*)out + (size_t)wid * COLS))[l] = o;
        }
    }
}

// ---------------- Layer-1 quad GEMM ----------------
__global__ __launch_bounds__(256) void gemm_l1_kernel(
    const float* __restrict__ x1a, const float* __restrict__ x1b, const float* __restrict__ x2a,
    const float* __restrict__ x2b, const float* __restrict__ Wi, unsigned short* __restrict__ H1,
    unsigned short* __restrict__ H2, int nrows) {
    constexpr int CG = 16;
    const float* X = (blockIdx.y == 0) ? x1a : (blockIdx.y == 1) ? x1b
                     : (blockIdx.y == 2) ? x2a : x2b;
    const float* W = Wi + (blockIdx.y & 1) * 128 * 64;
    unsigned short* Y = (blockIdx.y < 2) ? H1 : H2;
    int ocol = (int)(blockIdx.y & 1) * 64;
    __shared__ float Ws[32][64];
    __shared__ float Xs[64][32];
    int tid = threadIdx.x;
    int row0 = blockIdx.x * 64;
    int cg = tid % CG;
    int rg = tid / CG;
    float4 acc[4];
#pragma unroll
    for (int i = 0; i < 4; ++i) acc[i] = make_float4(0.f, 0.f, 0.f, 0.f);
    for (int kc = 0; kc < 4; ++kc) {
        for (int i = tid; i < 32 * CG; i += 256) {
            int r = i / CG, c = i % CG;
            *(float4*)&Ws[r][c * 4] = *(const float4*)(W + (size_t)(kc * 32 + r) * 64 + c * 4);
        }
        for (int i = tid; i < 64 * 8; i += 256) {
            int r = i / 8, c = i % 8;
            int gr = row0 + r;
            float4 v = make_float4(0.f, 0.f, 0.f, 0.f);
            if (gr < nrows) v = *(const float4*)(X + (size_t)gr * DFEAT + kc * 32 + c * 4);
            *(float4*)&Xs[r][c * 4] = v;
        }
        __syncthreads();
#pragma unroll
        for (int k = 0; k < 32; ++k) {
            float4 w = *(float4*)&Ws[k][cg * 4];
#pragma unroll
            for (int i = 0; i < 4; ++i) {
                float a = Xs[rg * 4 + i][k];
                acc[i].x = fmaf(a, w.x, acc[i].x);
                acc[i].y = fmaf(a, w.y, acc[i].y);
                acc[i].z = fmaf(a, w.z, acc[i].z);
                acc[i].w = fmaf(a, w.w, acc[i].w);
            }
        }
        __syncthreads();
    }
#pragma unroll
    for (int i = 0; i < 4; ++i) {
        int r = row0 + rg * 4 + i;
        if (r < nrows) {
            ushort4 o;
            o.x = f2bf(acc[i].x); o.y = f2bf(acc[i].y);
            o.z = f2bf(acc[i].z); o.w = f2bf(acc[i].w);
            *(ushort4*)(Y + (size_t)r * DFEAT + ocol + cg * 4) = o;
        }
    }
}

// ---------------- prepW: Wm (2x128x128 fp32) -> bf16 transposed [l][kc][col][kk] ----------------
__global__ __launch_bounds__(256) void prepW_kernel(const float* __restrict__ Wm,
                                                    unsigned short* __restrict__ Wt) {
    int o = blockIdx.x * 256 + threadIdx.x;  // 16384 per layer
    int l = blockIdx.y;
    int kk = o & 31;
    int col = (o >> 5) & 127;
    int kc = o >> 12;
    int k = kc * 32 + kk;
    Wt[(size_t)l * 16384 + o] = f2bf(Wm[(size_t)l * 16384 + (size_t)k * 128 + col]);
}

// ---------------- MFMA fused GEMM (128->128): x = w1*relu(bn(A)) + w2*relu(bn(B)) ----------------
// Block: 64 rows x 128 cols, 4 waves; wave w owns rows 16w..16w+15.
// A-frag: m=lane&15, k=quad*8+j. B-frag: n=lane&15, k=quad*8+j (from Wt, coalesced).
// C/D: col=lane&15, row=quad*4+reg.
__global__ __launch_bounds__(256) void gemm_mfma_kernel(
    const unsigned short* __restrict__ Abf, const unsigned short* __restrict__ Bbf,
    const float* __restrict__ ss, const float* __restrict__ wout,
    const unsigned short* __restrict__ Wt, unsigned short* __restrict__ Y, int nrows) {
    __shared__ short Xs[64][128];
    int tid = threadIdx.x;
    int row0 = blockIdx.x * 64;
    int wave = tid >> 6, lane = tid & 63;
    int m = lane & 15, quad = lane >> 4;
    float w1 = wout[0], w2 = wout[1];
    // stage fused X (bf16) — 1024 units of 8 elems
    for (int u = tid; u < 1024; u += 256) {
        int r = u >> 4;
        int col0 = (u & 15) * 8;
        int gr = row0 + r;
        if (gr < nrows) {
#pragma unroll
            for (int hh = 0; hh < 2; ++hh) {
                int c = col0 + hh * 4;
                float4 fa = bf4tof4(*(const ushort4*)(Abf + (size_t)gr * 128 + c));
                float4 fb = bf4tof4(*(const ushort4*)(Bbf + (size_t)gr * 128 + c));
                float4 sa = *(const float4*)(ss + c);
                float4 ha = *(const float4*)(ss + 128 + c);
                float4 sb = *(const float4*)(ss + 256 + c);
                float4 hb = *(const float4*)(ss + 384 + c);
                ushort4 o;
                o.x = f2bf(w1 * fmaxf(fmaf(fa.x, sa.x, ha.x), 0.f) +
                           w2 * fmaxf(fmaf(fb.x, sb.x, hb.x), 0.f));
                o.y = f2bf(w1 * fmaxf(fmaf(fa.y, sa.y, ha.y), 0.f) +
                           w2 * fmaxf(fmaf(fb.y, sb.y, hb.y), 0.f));
                o.z = f2bf(w1 * fmaxf(fmaf(fa.z, sa.z, ha.z), 0.f) +
                           w2 * fmaxf(fmaf(fb.z, sb.z, hb.z), 0.f));
                o.w = f2bf(w1 * fmaxf(fmaf(fa.w, sa.w, ha.w), 0.f) +
                           w2 * fmaxf(fmaf(fb.w, sb.w, hb.w), 0.f));
                *(ushort4*)&Xs[r][c] = o;
            }
        } else {
            ushort4 z = {0, 0, 0, 0};
            *(ushort4*)&Xs[r][col0] = z;
            *(ushort4*)&Xs[r][col0 + 4] = z;
        }
    }
    __syncthreads();
    f32x4 acc[8];
#pragma unroll
    for (int i = 0; i < 8; ++i) acc[i] = (f32x4){0.f, 0.f, 0.f, 0.f};
#pragma unroll
    for (int kc = 0; kc < 4; ++kc) {
        bf16x8 a = *(const bf16x8*)&Xs[wave * 16 + m][kc * 32 + quad * 8];
#pragma unroll
        for (int ct = 0; ct < 8; ++ct) {
            const short* bp = (const short*)(Wt + ((size_t)(kc * 128 + ct * 16 + m) * 32) + quad * 8);
            bf16x8 b = *(const bf16x8*)bp;
            acc[ct] = __builtin_amdgcn_mfma_f32_16x16x32_bf16(a, b, acc[ct], 0, 0, 0);
        }
    }
#pragma unroll
    for (int ct = 0; ct < 8; ++ct) {
#pragma unroll
        for (int i = 0; i < 4; ++i) {
            int gr = row0 + wave * 16 + quad * 4 + i;
            if (gr < nrows) Y[(size_t)gr * 128 + ct * 16 + m] = f2bf(acc[ct][i]);
        }
    }
}

// ---------------- VALU fused GEMM (final 128->40) ----------------
template <int CG, int RPT>
__global__ __launch_bounds__(256) void gemm_fused_kernel(
    const unsigned short* __restrict__ Abf, const unsigned short* __restrict__ Bbf,
    const float* __restrict__ ss, const float* __restrict__ wout, const float* __restrict__ W,
    unsigned short* __restrict__ Y, int nrows, int fout, int ostride) {
    __shared__ float Ws[32][CG * 4];
    __shared__ float Xs[64][32];
    int tid = threadIdx.x;
    int row0 = blockIdx.x * 64;
    int cg = tid % CG;
    int rg = tid / CG;
    float w1 = wout[0], w2 = wout[1];
    float4 acc[RPT];
#pragma unroll
    for (int i = 0; i < RPT; ++i) acc[i] = make_float4(0.f, 0.f, 0.f, 0.f);
    for (int kc = 0; kc < 4; ++kc) {
        for (int i = tid; i < 32 * CG; i += 256) {
            int r = i / CG, c = i % CG;
            float4 w;
            if ((c * 4 + 3) < fout) {
                w = *(const float4*)(W + (size_t)(kc * 32 + r) * fout + c * 4);
            } else {
                float t0 = (c * 4 + 0) < fout ? W[(size_t)(kc * 32 + r) * fout + c * 4 + 0] : 0.f;
                float t1 = (c * 4 + 1) < fout ? W[(size_t)(kc * 32 + r) * fout + c * 4 + 1] : 0.f;
                float t2 = (c * 4 + 2) < fout ? W[(size_t)(kc * 32 + r) * fout + c * 4 + 2] : 0.f;
                float t3 = (c * 4 + 3) < fout ? W[(size_t)(kc * 32 + r) * fout + c * 4 + 3] : 0.f;
                w = make_float4(t0, t1, t2, t3);
            }
            *(float4*)&Ws[r][c * 4] = w;
        }
        for (int i = tid; i < 64 * 8; i += 256) {
            int r = i / 8, c = i % 8;
            int gr = row0 + r;
            int col0 = kc * 32 + c * 4;
            float4 v = make_float4(0.f, 0.f, 0.f, 0.f);
            if (gr < nrows) {
                float4 a = bf4tof4(*(const ushort4*)(Abf + (size_t)gr * DFEAT + col0));
                float4 b = bf4tof4(*(const ushort4*)(Bbf + (size_t)gr * DFEAT + col0));
                float4 scA = *(const float4*)(ss + col0);
                float4 shA = *(const float4*)(ss + DFEAT + col0);
                float4 scB = *(const float4*)(ss + 2 * DFEAT + col0);
                float4 shB = *(const float4*)(ss + 3 * DFEAT + col0);
                v.x = w1 * fmaxf(fmaf(a.x, scA.x, shA.x), 0.f) +
                      w2 * fmaxf(fmaf(b.x, scB.x, shB.x), 0.f);
                v.y = w1 * fmaxf(fmaf(a.y, scA.y, shA.y), 0.f) +
                      w2 * fmaxf(fmaf(b.y, scB.y, shB.y), 0.f);
                v.z = w1 * fmaxf(fmaf(a.z, scA.z, shA.z), 0.f) +
                      w2 * fmaxf(fmaf(b.z, scB.z, shB.z), 0.f);
                v.w = w1 * fmaxf(fmaf(a.w, scA.w, shA.w), 0.f) +
                      w2 * fmaxf(fmaf(b.w, scB.w, shB.w), 0.f);
            }
            *(float4*)&Xs[r][c * 4] = v;
        }
        __syncthreads();
#pragma unroll
        for (int k = 0; k < 32; ++k) {
            float4 w = *(float4*)&Ws[k][cg * 4];
#pragma unroll
            for (int i = 0; i < RPT; ++i) {
                float a = Xs[rg * RPT + i][k];
                acc[i].x = fmaf(a, w.x, acc[i].x);
                acc[i].y = fmaf(a, w.y, acc[i].y);
                acc[i].z = fmaf(a, w.z, acc[i].z);
                acc[i].w = fmaf(a, w.w, acc[i].w);
            }
        }
        __syncthreads();
    }
    if (cg * 4 < fout) {
#pragma unroll
        for (int i = 0; i < RPT; ++i) {
            int r = row0 + rg * RPT + i;
            if (r < nrows) {
                ushort4 o;
                o.x = f2bf(acc[i].x); o.y = f2bf(acc[i].y);
                o.z = f2bf(acc[i].z); o.w = f2bf(acc[i].w);
                *(ushort4*)(Y + (size_t)r * ostride + cg * 4) = o;
            }
        }
    }
}

// ---------------- BN statistics: 2-level atomicAdd ----------------
__global__ __launch_bounds__(256) void stats2_kernel(const unsigned short* __restrict__ A,
                                                     const unsigned short* __restrict__ B,
                                                     float* __restrict__ stats, int nrows) {
    __shared__ float red1[256];
    __shared__ float red2[256];
    int t = threadIdx.x;
    int col = t & 127;
    int rg = t >> 7;
    const unsigned short* src = (blockIdx.y == 0) ? A : B;
    float* st = stats + (size_t)blockIdx.y * 256;
    int r0 = blockIdx.x * 128 + rg * 64;
    int r1 = min(r0 + 64, nrows);
    float s = 0.f, s2 = 0.f;
    for (int r = r0; r < r1; ++r) {
        float v = bf2f(src[(size_t)r * DFEAT + col]);
        s += v;
        s2 = fmaf(v, v, s2);
    }
    red1[t] = s;
    red2[t] = s2;
    __syncthreads();
    if (t < 128) {
        atomicAdd(&st[col], red1[t] + red1[t + 128]);
        atomicAdd(&st[DFEAT + col], red2[t] + red2[t + 128]);
    }
}

// ---------------- BN scale/shift + gates; zeros stats for next layer ----------------
__global__ __launch_bounds__(128) void gate_prep_kernel(
    float* __restrict__ statsA, float* __restrict__ statsB,
    const unsigned short* __restrict__ preA, const unsigned short* __restrict__ preB,
    const float* __restrict__ gamma, const float* __restrict__ beta,
    const float* __restrict__ gwA, const float* __restrict__ gbA,
    const float* __restrict__ gwB, const float* __restrict__ gbB,
    float* __restrict__ ss, float* __restrict__ wout, int nrows) {
    __shared__ float red[128];
    __shared__ float dotA_s;
    int t = threadIdx.x;
    float invN = 1.f / (float)nrows;
    float meanA = statsA[t] * invN;
    float varA = statsA[DFEAT + t] * invN - meanA * meanA;
    float scA = gamma[t] * rsqrtf(varA + 1e-5f);
    float shA = beta[t] - meanA * scA;
    ss[t] = scA;
    ss[DFEAT + t] = shA;
    float meanB = statsB[t] * invN;
    float varB = statsB[DFEAT + t] * invN - meanB * meanB;
    float scB = gamma[t] * rsqrtf(varB + 1e-5f);
    float shB = beta[t] - meanB * scB;
    ss[2 * DFEAT + t] = scB;
    ss[3 * DFEAT + t] = shB;
    statsA[t] = 0.f;
    statsA[DFEAT + t] = 0.f;
    statsB[t] = 0.f;
    statsB[DFEAT + t] = 0.f;
    float av = fmaxf(fmaf(bf2f(preA[(size_t)(nrows - 1) * DFEAT + t]), scA, shA), 0.f);
    red[t] = av * gwA[t];
    __syncthreads();
    for (int s = 64; s > 0; s >>= 1) {
        if (t < s) red[t] += red[t + s];
        __syncthreads();
    }
    if (t == 0) dotA_s = red[0];
    __syncthreads();
    float bv = fmaxf(fmaf(bf2f(preB[(size_t)(nrows - 1) * DFEAT + t]), scB, shB), 0.f);
    red[t] = bv * gwB[t];
    __syncthreads();
    for (int s = 64; s > 0; s >>= 1) {
        if (t < s) red[t] += red[t + s];
        __syncthreads();
    }
    if (t == 0) {
        float s1 = 1.f / (1.f + expf(-(dotA_s + gbA[0])));
        float s2 = 1.f / (1.f + expf(-(red[0] + gbB[0])));
        float tt = s1 + s2;
        wout[0] = s1 / tt;
        wout[1] = s2 / tt;
    }
}

__global__ __launch_bounds__(64) void gate_final_kernel(
    const float* __restrict__ p1, const float* __restrict__ p2,
    const float* __restrict__ w1v, const float* __restrict__ b1,
    const float* __restrict__ w2v, const float* __restrict__ b2,
    float* __restrict__ wout, int nrows, int nclass) {
    __shared__ float red[64];
    __shared__ float dot1_s;
    int t = threadIdx.x;
    float v = (t < nclass) ? p1[(size_t)(nrows - 1) * nclass + t] * w1v[t] : 0.f;
    red[t] = v;
    __syncthreads();
    for (int s = 32; s > 0; s >>= 1) {
        if (t < s) red[t] += red[t + s];
        __syncthreads();
    }
    if (t == 0) dot1_s = red[0];
    __syncthreads();
    v = (t < nclass) ? p2[(size_t)(nrows - 1) * nclass + t] * w2v[t] : 0.f;
    red[t] = v;
    __syncthreads();
    for (int s = 32; s > 0; s >>= 1) {
        if (t < s) red[t] += red[t + s];
        __syncthreads();
    }
    if (t == 0) {
        float s1 = 1.f / (1.f + expf(-(dot1_s + b1[0])));
        float s2 = 1.f / (1.f + expf(-(red[0] + b2[0])));
        float tt = s1 + s2;
        wout[0] = s1 / tt;
        wout[1] = s2 / tt;
    }
}

__global__ __launch_bounds__(256) void mix_kernel(const float* __restrict__ p1,
                                                  const float* __restrict__ p2,
                                                  const float* __restrict__ wout,
                                                  float* __restrict__ o, int n4) {
    int idx = blockIdx.x * blockDim.x + threadIdx.x;
    if (idx >= n4) return;
    float w1 = wout[0], w2 = wout[1];
    float4 a = *(const float4*)(p1 + (size_t)idx * 4);
    float4 b = *(const float4*)(p2 + (size_t)idx * 4);
    float4 r = make_float4(w1 * a.x + w2 * b.x, w1 * a.y + w2 * b.y, w1 * a.z + w2 * b.z,
                           w1 * a.w + w2 * b.w);
    *(float4*)(o + (size_t)idx * 4) = r;
}

extern "C" void kernel_launch(void* const* d_in, const int* in_sizes, int n_in, void* d_out,
                              int out_size, void* d_ws, size_t ws_size, hipStream_t stream) {
    (void)n_in; (void)out_size; (void)ws_size;
    const int N = in_sizes[0] / DFEAT;        // 50000
    const int E = in_sizes[4] / 2;            // 800000
    const int NC = in_sizes[15];              // 40

    const float* x1a = (const float*)d_in[0];
    const float* x1b = (const float*)d_in[1];
    const float* x2a = (const float*)d_in[2];
    const float* x2b = (const float*)d_in[3];
    const int* ei1 = (const int*)d_in[4];
    const int* ei2 = (const int*)d_in[5];
    const float* Wi = (const float*)d_in[6];
    const float* bi = (const float*)d_in[7];
    const float* gi = (const float*)d_in[8];
    const float* bei = (const float*)d_in[9];
    const float* Wm = (const float*)d_in[10];
    const float* bm = (const float*)d_in[11];
    const float* gm = (const float*)d_in[12];
    const float* bem = (const float*)d_in[13];
    const float* Wf = (const float*)d_in[14];
    const float* bf = (const float*)d_in[15];
    const float* fc1w1_W = (const float*)d_in[16];
    const float* fc1w1_b = (const float*)d_in[17];
    const float* fc1w2_W = (const float*)d_in[18];
    const float* fc1w2_b = (const float*)d_in[19];
    const float* aws_w1_W = (const float*)d_in[20];
    const float* aws_w1_b = (const float*)d_in[21];
    const float* aws_w2_W = (const float*)d_in[22];
    const float* aws_w2_b = (const float*)d_in[23];
    const float* fcw1_W = (const float*)d_in[24];
    const float* fcw1_b = (const float*)d_in[25];
    const float* fcw2_W = (const float*)d_in[26];
    const float* fcw2_b = (const float*)d_in[27];

    char* ws = (char*)d_ws;
    size_t off = 0;
    auto alloc = [&](size_t bytes) -> char* {
        char* p = ws + off;
        off += (bytes + 255) & ~(size_t)255;
        return p;
    };
    unsigned short* A = (unsigned short*)alloc((size_t)N * DFEAT * 2);
    unsigned short* B = (unsigned short*)alloc((size_t)N * DFEAT * 2);
    unsigned short* H1 = (unsigned short*)alloc((size_t)N * DFEAT * 2);
    unsigned short* H2 = (unsigned short*)alloc((size_t)N * DFEAT * 2);
    int* rp1 = (int*)alloc((size_t)(N + 1) * 4);
    int* rp2 = (int*)alloc((size_t)(N + 1) * 4);
    int* zb = (int*)alloc((size_t)4 * N * 4);  // cnt1|cnt2|fl1|fl2 — one memset
    int* cnt1 = zb;
    int* cnt2 = zb + N;
    int* fl1 = zb + 2 * N;
    int* fl2 = zb + 3 * N;
    float* dv1 = (float*)alloc((size_t)N * 4);
    float* dv2 = (float*)alloc((size_t)N * 4);
    int* cs1 = (int*)alloc((size_t)E * 4);
    int* cs2 = (int*)alloc((size_t)E * 4);
    unsigned short* Wt = (unsigned short*)alloc((size_t)2 * 16384 * 2);
    float* stats = (float*)alloc(2048);
    float* statsA = stats;
    float* statsB = stats + 256;
    float* ssbuf = (float*)alloc(2048);
    float* wout = (float*)alloc(256);
    int nb = (N + 2047) / 2048;  // 25
    int* bsums = (int*)alloc((size_t)2 * nb * 4);

    const int* src1 = ei1;
    const int* dst1 = ei1 + E;
    const int* src2 = ei2;
    const int* dst2 = ei2 + E;

    int ebl = (E + 255) / 256;
    int gemmbl = (N + 63) / 64;
    dim3 dualgrid(ebl, 2);
    dim3 agggrid((N + 3) / 4, 2);
    dim3 statgrid((N + 127) / 128, 2);
    dim3 scangrid(nb, 2);
    dim3 l1grid(gemmbl, 4);
    dim3 prepgrid(64, 2);

    // ---- CSR build + weight prep ----
    hipMemsetAsync(zb, 0, (size_t)4 * N * 4, stream);
    prepW_kernel<<<prepgrid, 256, 0, stream>>>(Wm, Wt);
    count_kernel<<<dualgrid, 256, 0, stream>>>(dst1, dst2, cnt1, cnt2, E);
    blocksum_kernel<<<scangrid, 256, 0, stream>>>(cnt1, cnt2, bsums, N, nb);
    scansums_kernel<<<1, 64, 0, stream>>>(bsums, nb, rp1, rp2, N, E, stats);
    writerp_kernel<<<scangrid, 256, 0, stream>>>(cnt1, cnt2, bsums, rp1, rp2, dv1, dv2, N, nb);
    fill_kernel<<<dualgrid, 256, 0, stream>>>(src1, dst1, src2, dst2, rp1, rp2, fl1, fl2, cs1,
                                              cs2, E);

    // ---- Layer 1 ----
    gemm_l1_kernel<<<l1grid, 256, 0, stream>>>(x1a, x1b, x2a, x2b, Wi, H1, H2, N);
    dualagg_kernel<32, unsigned short><<<agggrid, 256, 0, stream>>>(
        H1, H2, rp1, cs1, dv1, rp2, cs2, dv2, bi, A, B, N);
    stats2_kernel<<<statgrid, 256, 0, stream>>>(A, B, stats, N);
    gate_prep_kernel<<<1, 128, 0, stream>>>(statsA, statsB, A, B, gi, bei, fc1w1_W, fc1w1_b,
                                            fc1w2_W, fc1w2_b, ssbuf, wout, N);

    // ---- Middle layer 0 (MFMA fused GEMM) ----
    gemm_mfma_kernel<<<gemmbl, 256, 0, stream>>>(A, B, ssbuf, wout, Wt, H1, N);
    dualagg_kernel<32, unsigned short><<<agggrid, 256, 0, stream>>>(
        H1, H1, rp1, cs1, dv1, rp2, cs2, dv2, bm, A, B, N);
    stats2_kernel<<<statgrid, 256, 0, stream>>>(A, B, stats, N);
    gate_prep_kernel<<<1, 128, 0, stream>>>(statsA, statsB, A, B, gm, bem, aws_w1_W, aws_w1_b,
                                            aws_w2_W, aws_w2_b, ssbuf, wout, N);

    // ---- Middle layer 1 ----
    gemm_mfma_kernel<<<gemmbl, 256, 0, stream>>>(A, B, ssbuf, wout, Wt + 16384, H1, N);
    dualagg_kernel<32, unsigned short><<<agggrid, 256, 0, stream>>>(
        H1, H1, rp1, cs1, dv1, rp2, cs2, dv2, bm + 128, A, B, N);
    stats2_kernel<<<statgrid, 256, 0, stream>>>(A, B, stats, N);
    gate_prep_kernel<<<1, 128, 0, stream>>>(statsA, statsB, A, B, gm + 128, bem + 128,
                                            aws_w1_W + 128, aws_w1_b + 1, aws_w2_W + 128,
                                            aws_w2_b + 1, ssbuf, wout, N);

    // ---- Final layer ----
    float* out0 = (float*)d_out;
    float* p1 = out0 + (size_t)N * NC;
    float* p2 = out0 + (size_t)2 * N * NC;
    gemm_fused_kernel<16, 4><<<gemmbl, 256, 0, stream>>>(A, B, ssbuf, wout, Wf, H2, N, NC, NC);
    dualagg_kernel<10, float><<<agggrid, 256, 0, stream>>>(H2, H2, rp1, cs1, dv1, rp2, cs2, dv2,
                                                           bf, p1, p2, N);
    gate_final_kernel<<<1, 64, 0, stream>>>(p1, p2, fcw1_W, fcw1_b, fcw2_W, fcw2_b, wout, N, NC);
    mix_kernel<<<(N * NC / 4 + 255) / 256, 256, 0, stream>>>(p1, p2, wout, out0, N * NC / 4);
}